// Round 1
// baseline (1700.099 us; speedup 1.0000x reference)
//
#include <hip/hip_runtime.h>
#include <hip/hip_bf16.h>

#define NTOK 8192   // B*T tokens
#define DDIM 1024
#define FDIM 2048
#define NEXP 16
#define BM   64     // tokens per FFN block
#define FC   256    // F-chunk per fused iteration
#define KC1  64     // K-chunk for GEMM1 staging (K = D)
#define KC2  32     // K-chunk for GEMM2 staging (K = FC)

// LDS layout (bytes)
#define SM_XS 0                 // ushort [64][72]   = 9216
#define SM_W1 9216              // ushort [256][72]  = 36864
#define SM_UT 46080             // ushort [64][264]  = 33792
#define SM_W2 79872             // ushort [1024][40] = 81920
#define SM_TK 161792            // int    [64]       = 256
#define SM_WG 162048            // float  [64]       = 256
#define SM_TOTAL 162304

typedef short bf16x8 __attribute__((ext_vector_type(8)));
typedef float f32x4  __attribute__((ext_vector_type(4)));

__device__ __forceinline__ unsigned short f2bf(float f) {
  unsigned int u = __builtin_bit_cast(unsigned int, f);
  u += 0x7fffu + ((u >> 16) & 1u);            // RNE
  return (unsigned short)(u >> 16);
}
__device__ __forceinline__ unsigned int pk2(float a, float b) {
  return (unsigned int)f2bf(a) | ((unsigned int)f2bf(b) << 16);
}
__device__ __forceinline__ float silu_f(float s) {
  return s / (1.f + __expf(-s));
}

// ---------------- gate: logits -> top2 -> softmax -> per-expert lists ----------------
__global__ __launch_bounds__(256) void gate_kernel(
    const float* __restrict__ x, const float* __restrict__ Wg,
    int* __restrict__ counts, int* __restrict__ tokl, float* __restrict__ wgtl) {
  int gtid = blockIdx.x * blockDim.x + threadIdx.x;
  int tok = gtid >> 6;
  int lane = threadIdx.x & 63;
  if (tok >= NTOK) return;
  const float* xr = x + (size_t)tok * DDIM;
  float xv[16];
#pragma unroll
  for (int j = 0; j < 16; ++j) xv[j] = xr[lane + 64 * j];
  float lg[NEXP];
#pragma unroll
  for (int e = 0; e < NEXP; ++e) {
    float s = 0.f;
#pragma unroll
    for (int j = 0; j < 16; ++j) s += xv[j] * Wg[(lane + 64 * j) * NEXP + e];
#pragma unroll
    for (int off = 32; off > 0; off >>= 1) s += __shfl_xor(s, off);
    lg[e] = s;
  }
  // top-2, top_k tie-break (earliest index wins on ties via strict >)
  int e0 = 0; float b0 = lg[0];
#pragma unroll
  for (int e = 1; e < NEXP; ++e) if (lg[e] > b0) { b0 = lg[e]; e0 = e; }
  int e1 = -1; float b1 = -3.4e38f;
#pragma unroll
  for (int e = 0; e < NEXP; ++e) if (e != e0 && lg[e] > b1) { b1 = lg[e]; e1 = e; }
  float t = expf(b1 - b0);
  float w0 = 1.f / (1.f + t);
  float w1 = t / (1.f + t);
  if (lane == 0) {
    int p = atomicAdd(&counts[e0], 1);
    tokl[e0 * NTOK + p] = tok; wgtl[e0 * NTOK + p] = w0;
    p = atomicAdd(&counts[e1], 1);
    tokl[e1 * NTOK + p] = tok; wgtl[e1 * NTOK + p] = w1;
  }
}

// ---------------- fused FFN: y[tile] += w * silu(X W1e) W2e ----------------
__global__ __launch_bounds__(512, 2) void ffn_kernel(
    const float* __restrict__ x, const float* __restrict__ W1,
    const float* __restrict__ W2, const int* __restrict__ counts,
    const int* __restrict__ tokl, const float* __restrict__ wgtl,
    float* __restrict__ out) {
  int e = blockIdx.y;
  int cnt = counts[e];
  int base = blockIdx.x * BM;
  if (base >= cnt) return;
  int m = min(BM, cnt - base);

  extern __shared__ char smem[];
  unsigned short* xs  = (unsigned short*)(smem + SM_XS);   // [64][72]  X (r,k) bf16
  unsigned short* w1t = (unsigned short*)(smem + SM_W1);   // [256][72] W1^T (f,k)
  unsigned short* ut  = (unsigned short*)(smem + SM_UT);   // [64][264] U (r,f)
  unsigned short* w2t = (unsigned short*)(smem + SM_W2);   // [1024][40] W2^T (c,k)
  int*   tks = (int*)(smem + SM_TK);
  float* wgs = (float*)(smem + SM_WG);

  int tid = threadIdx.x;
  int wid = tid >> 6;
  int lane = tid & 63;
  int lhi = lane >> 4;     // 0..3
  int llo = lane & 15;     // 0..15

  if (tid < BM) {
    int tk = 0; float w = 0.f;
    if (tid < m) { tk = tokl[e * NTOK + base + tid]; w = wgtl[e * NTOK + base + tid]; }
    tks[tid] = tk; wgs[tid] = w;
  }
  __syncthreads();

  const float* W1e = W1 + (size_t)e * DDIM * FDIM;  // [D][F]
  const float* W2e = W2 + (size_t)e * FDIM * DDIM;  // [F][D]

  const int fwb = (wid >> 1) * 64;   // GEMM1: wave's f-range base (4 groups x 64)
  const int rwb = (wid & 1) * 32;    // GEMM1: wave's r-range base (2 groups x 32)
  const int cwb = wid * 128;         // GEMM2: wave's c-range base (8 x 128)

  f32x4 acc[4][8];                   // GEMM2 Y acc: r-frags 4 (all 64 rows) x c-frags 8
#pragma unroll
  for (int i = 0; i < 4; ++i)
#pragma unroll
    for (int j = 0; j < 8; ++j) acc[i][j] = (f32x4){0.f, 0.f, 0.f, 0.f};

  for (int fc = 0; fc < FDIM; fc += FC) {
    // ================= GEMM1: U' [FC][BM] = (W1e chunk)^T X^T, swapped operands =================
    f32x4 acc1[4][2];
#pragma unroll
    for (int i = 0; i < 4; ++i)
#pragma unroll
      for (int j = 0; j < 2; ++j) acc1[i][j] = (f32x4){0.f, 0.f, 0.f, 0.f};

    for (int kc = 0; kc < DDIM; kc += KC1) {
      __syncthreads();   // prior reads of xs/w1t (or prior GEMM2) complete
      { // stage X chunk: 64 r x 64 k, one octet per thread
        int r = tid >> 3, ko = tid & 7;
        float4 v0, v1;
        if (r < m) {
          const float* p = x + (size_t)tks[r] * DDIM + kc + ko * 8;
          v0 = *(const float4*)p; v1 = *(const float4*)(p + 4);
        } else {
          v0 = make_float4(0.f, 0.f, 0.f, 0.f); v1 = v0;
        }
        uint4 pk;
        pk.x = pk2(v0.x, v0.y); pk.y = pk2(v0.z, v0.w);
        pk.z = pk2(v1.x, v1.y); pk.w = pk2(v1.z, v1.w);
        *(uint4*)&xs[r * 72 + ko * 8] = pk;
      }
      // stage W1^T chunk: 64 k x 256 f, transposed, k-pair packed b32 writes
#pragma unroll
      for (int it = 0; it < 2; ++it) {
        int task = tid + 512 * it;          // 1024 tasks: (kp 0..31) x (fo 0..31)
        int kp = task & 31, fo = task >> 5;
        const float* p0 = W1e + (size_t)(kc + kp * 2) * FDIM + fc + fo * 8;
        const float* p1 = p0 + FDIM;
        float4 a0 = *(const float4*)p0, a1 = *(const float4*)(p0 + 4);
        float4 b0 = *(const float4*)p1, b1 = *(const float4*)(p1 + 4);
        unsigned int* wb0 = (unsigned int*)&w1t[(size_t)(fo * 8 + 0) * 72 + kp * 2];
        float av[8] = {a0.x,a0.y,a0.z,a0.w,a1.x,a1.y,a1.z,a1.w};
        float bv[8] = {b0.x,b0.y,b0.z,b0.w,b1.x,b1.y,b1.z,b1.w};
#pragma unroll
        for (int j = 0; j < 8; ++j)
          *(unsigned int*)&w1t[(size_t)(fo * 8 + j) * 72 + kp * 2] = pk2(av[j], bv[j]);
        (void)wb0;
      }
      __syncthreads();
      // compute: 2 k-steps of 32
#pragma unroll
      for (int ks = 0; ks < KC1; ks += 32) {
        bf16x8 af[4], bx[2];
#pragma unroll
        for (int fi = 0; fi < 4; ++fi)
          af[fi] = *(const bf16x8*)&w1t[(size_t)(fwb + fi * 16 + llo) * 72 + ks + lhi * 8];
#pragma unroll
        for (int ri = 0; ri < 2; ++ri)
          bx[ri] = *(const bf16x8*)&xs[(size_t)(rwb + ri * 16 + llo) * 72 + ks + lhi * 8];
#pragma unroll
        for (int fi = 0; fi < 4; ++fi)
#pragma unroll
          for (int ri = 0; ri < 2; ++ri)
            acc1[fi][ri] = __builtin_amdgcn_mfma_f32_16x16x32_bf16(
                af[fi], bx[ri], acc1[fi][ri], 0, 0, 0);
      }
    }
    // silu -> U in LDS (D' rows = f (4 consecutive per lane), cols = r)
#pragma unroll
    for (int fi = 0; fi < 4; ++fi)
#pragma unroll
      for (int ri = 0; ri < 2; ++ri) {
        int r  = rwb + ri * 16 + llo;
        int fb = fwb + fi * 16 + 4 * lhi;
        float u0 = silu_f(acc1[fi][ri][0]);
        float u1 = silu_f(acc1[fi][ri][1]);
        float u2 = silu_f(acc1[fi][ri][2]);
        float u3 = silu_f(acc1[fi][ri][3]);
        uint2 pv; pv.x = pk2(u0, u1); pv.y = pk2(u2, u3);
        *(uint2*)&ut[(size_t)r * 264 + fb] = pv;
      }
    __syncthreads();   // U visible

    // ================= GEMM2: Y[64][1024] += U [64][FC] @ W2e[fc:fc+FC][:] =================
    for (int kc2 = 0; kc2 < FC; kc2 += KC2) {
      // stage W2^T chunk: 32 k x 1024 c, transposed, k-pair b32 writes
#pragma unroll
      for (int it = 0; it < 4; ++it) {
        int task = tid + 512 * it;          // 2048 tasks: (kp 0..15) x (co 0..127)
        int kp = task & 15, co = task >> 4;
        const float* p0 = W2e + (size_t)(fc + kc2 + kp * 2) * DDIM + co * 8;
        const float* p1 = p0 + DDIM;
        float4 a0 = *(const float4*)p0, a1 = *(const float4*)(p0 + 4);
        float4 b0 = *(const float4*)p1, b1 = *(const float4*)(p1 + 4);
        float av[8] = {a0.x,a0.y,a0.z,a0.w,a1.x,a1.y,a1.z,a1.w};
        float bv[8] = {b0.x,b0.y,b0.z,b0.w,b1.x,b1.y,b1.z,b1.w};
#pragma unroll
        for (int j = 0; j < 8; ++j)
          *(unsigned int*)&w2t[(size_t)(co * 8 + j) * 40 + kp * 2] = pk2(av[j], bv[j]);
      }
      __syncthreads();
      bf16x8 au[4], bw[8];
#pragma unroll
      for (int ri = 0; ri < 4; ++ri)
        au[ri] = *(const bf16x8*)&ut[(size_t)(ri * 16 + llo) * 264 + kc2 + lhi * 8];
#pragma unroll
      for (int ci = 0; ci < 8; ++ci)
        bw[ci] = *(const bf16x8*)&w2t[(size_t)(cwb + ci * 16 + llo) * 40 + lhi * 8];
#pragma unroll
      for (int ri = 0; ri < 4; ++ri)
#pragma unroll
        for (int ci = 0; ci < 8; ++ci)
          acc[ri][ci] = __builtin_amdgcn_mfma_f32_16x16x32_bf16(
              au[ri], bw[ci], acc[ri][ci], 0, 0, 0);
      __syncthreads();   // done reading w2t before next restage
    }
  }

  // epilogue: y[tok[r]][c] += w[r] * acc
#pragma unroll
  for (int ri = 0; ri < 4; ++ri)
#pragma unroll
    for (int reg = 0; reg < 4; ++reg) {
      int r = ri * 16 + 4 * lhi + reg;
      if (r < m) {
        float w = wgs[r];
        size_t orow = (size_t)tks[r] * DDIM;
#pragma unroll
        for (int ci = 0; ci < 8; ++ci)
          atomicAdd(&out[orow + cwb + ci * 16 + llo], acc[ri][ci][reg] * w);
      }
    }
}

extern "C" void kernel_launch(void* const* d_in, const int* in_sizes, int n_in,
                              void* d_out, int out_size, void* d_ws, size_t ws_size,
                              hipStream_t stream) {
  const float* x  = (const float*)d_in[0];
  const float* Wg = (const float*)d_in[1];
  const float* W1 = (const float*)d_in[2];
  const float* W2 = (const float*)d_in[3];
  float* out = (float*)d_out;

  int*   counts = (int*)d_ws;                                   // 256 B
  int*   tokl   = (int*)((char*)d_ws + 256);                    // 512 KB
  float* wgtl   = (float*)((char*)d_ws + 256 + NTOK * NEXP * 4);// 512 KB

  hipFuncSetAttribute((const void*)ffn_kernel,
                      hipFuncAttributeMaxDynamicSharedMemorySize, SM_TOTAL);

  hipMemsetAsync(counts, 0, 256, stream);
  hipMemsetAsync(d_out, 0, (size_t)out_size * sizeof(float), stream);

  gate_kernel<<<NTOK / 4, 256, 0, stream>>>(x, Wg, counts, tokl, wgtl);

  dim3 g(NTOK / BM, NEXP);
  ffn_kernel<<<g, 512, SM_TOTAL, stream>>>(x, W1, W2, counts, tokl, wgtl, out);
}

// Round 2
// 1170.338 us; speedup vs baseline: 1.4527x; 1.4527x over previous
//
#include <hip/hip_runtime.h>
#include <hip/hip_bf16.h>

#define NTOK 8192   // B*T tokens
#define DDIM 1024
#define FDIM 2048
#define NEXP 16

// ---------------- workspace layout (bytes) ----------------
#define WS_COUNTS 0
#define WS_TOKL   4096
#define WS_WGTL   (4096 + NTOK*NEXP*4)
#define WS_XBF    (size_t)(2u<<20)    // 16 MiB bf16 x
#define WS_W1S    (size_t)(32u<<20)   // 64 MiB bf16 W1 frag-ordered
#define WS_W2S    (size_t)(96u<<20)   // 64 MiB bf16 W2 frag-ordered
#define WS_NEED   (size_t)(160u<<20)

// ---------------- new ffn LDS layout (bytes) ----------------
#define F2_XS 0          // [64][1024] bf16, rows 2048 B, 16B-slot XOR swizzle
#define F2_UT 131072     // [64][128]  bf16, rows 256 B, swizzled
#define F2_TK 147456     // int[64]
#define F2_WG 147712     // float[64]
#define F2_TOTAL 147968

// ---------------- old (fallback) ffn LDS layout ----------------
#define SM_XS 0
#define SM_W1 9216
#define SM_UT 46080
#define SM_W2 79872
#define SM_TK 161792
#define SM_WG 162048
#define SM_TOTAL 162304

typedef short bf16x8 __attribute__((ext_vector_type(8)));
typedef float f32x4  __attribute__((ext_vector_type(4)));

__device__ __forceinline__ unsigned short f2bf(float f) {
  unsigned int u = __builtin_bit_cast(unsigned int, f);
  u += 0x7fffu + ((u >> 16) & 1u);            // RNE
  return (unsigned short)(u >> 16);
}
__device__ __forceinline__ unsigned int pk2(float a, float b) {
  return (unsigned int)f2bf(a) | ((unsigned int)f2bf(b) << 16);
}
__device__ __forceinline__ float silu_f(float s) {
  return s / (1.f + __expf(-s));
}
__device__ __forceinline__ void gld_lds16(const void* g, void* l) {
  __builtin_amdgcn_global_load_lds((const __attribute__((address_space(1))) void*)g,
                                   (__attribute__((address_space(3))) void*)l, 16, 0, 0);
}

// ---------------- gate: logits -> top2 -> softmax -> per-expert lists ----------------
__global__ __launch_bounds__(256) void gate_kernel(
    const float* __restrict__ x, const float* __restrict__ Wg,
    int* __restrict__ counts, int* __restrict__ tokl, float* __restrict__ wgtl) {
  int gtid = blockIdx.x * blockDim.x + threadIdx.x;
  int tok = gtid >> 6;
  int lane = threadIdx.x & 63;
  if (tok >= NTOK) return;
  const float* xr = x + (size_t)tok * DDIM;
  float xv[16];
#pragma unroll
  for (int j = 0; j < 16; ++j) xv[j] = xr[lane + 64 * j];
  float lg[NEXP];
#pragma unroll
  for (int e = 0; e < NEXP; ++e) {
    float s = 0.f;
#pragma unroll
    for (int j = 0; j < 16; ++j) s += xv[j] * Wg[(lane + 64 * j) * NEXP + e];
#pragma unroll
    for (int off = 32; off > 0; off >>= 1) s += __shfl_xor(s, off);
    lg[e] = s;
  }
  int e0 = 0; float b0 = lg[0];
#pragma unroll
  for (int e = 1; e < NEXP; ++e) if (lg[e] > b0) { b0 = lg[e]; e0 = e; }
  int e1 = -1; float b1 = -3.4e38f;
#pragma unroll
  for (int e = 0; e < NEXP; ++e) if (e != e0 && lg[e] > b1) { b1 = lg[e]; e1 = e; }
  float t = expf(b1 - b0);
  float w0 = 1.f / (1.f + t);
  float w1 = t / (1.f + t);
  if (lane == 0) {
    int p = atomicAdd(&counts[e0], 1);
    tokl[e0 * NTOK + p] = tok; wgtl[e0 * NTOK + p] = w0;
    p = atomicAdd(&counts[e1], 1);
    tokl[e1 * NTOK + p] = tok; wgtl[e1 * NTOK + p] = w1;
  }
}

// ---------------- x fp32 -> bf16 row-major ----------------
__global__ __launch_bounds__(512) void convert_x(const float* __restrict__ x,
                                                 unsigned short* __restrict__ xbf) {
  int i = blockIdx.x * 512 + threadIdx.x;   // over 2,097,152 float4s (exact)
  float4 v = ((const float4*)x)[i];
  uint2 o; o.x = pk2(v.x, v.y); o.y = pk2(v.z, v.w);
  ((uint2*)xbf)[i] = o;
}

// ---------------- W1/W2 fp32 -> bf16, MFMA-fragment-ordered ----------------
// W1s chunk gid = (e*128 + ff)*32 + kk : 1KB, lane(llo,lhi), j:
//   val = bf16(W1[e][kk*32+lhi*8+j][ff*16+llo])
// W2s chunk g   = (e*64 + kk)*64 + cc :
//   val = bf16(W2[e][kk*32+lhi*8+j][cc*16+llo])
__global__ __launch_bounds__(512) void convert_w(
    const float* __restrict__ W1, const float* __restrict__ W2,
    unsigned short* __restrict__ W1s, unsigned short* __restrict__ W2s) {
  int gid = blockIdx.x * 8 + (threadIdx.x >> 6);
  int lane = threadIdx.x & 63, llo = lane & 15, lhi = lane >> 4;
  const float* src;
  unsigned short* dst;
  int C;
  if (gid < 65536) {
    int e = gid >> 12, ff = (gid >> 5) & 127, kk = gid & 31;
    src = W1 + ((size_t)e << 21) + (size_t)(kk * 32 + lhi * 8) * FDIM + ff * 16 + llo;
    dst = W1s + ((size_t)gid << 9) + lane * 8;
    C = FDIM;
  } else {
    int g = gid - 65536;
    int e = g >> 12, kk = (g >> 6) & 63, cc = g & 63;
    src = W2 + ((size_t)e << 21) + (size_t)(kk * 32 + lhi * 8) * DDIM + cc * 16 + llo;
    dst = W2s + ((size_t)g << 9) + lane * 8;
    C = DDIM;
  }
  float v[8];
#pragma unroll
  for (int j = 0; j < 8; ++j) v[j] = src[(size_t)j * C];
  uint4 o;
  o.x = pk2(v[0], v[1]); o.y = pk2(v[2], v[3]);
  o.z = pk2(v[4], v[5]); o.w = pk2(v[6], v[7]);
  *(uint4*)dst = o;
}

// ---------------- fused FFN v2: weights direct from global, X resident in LDS ----------------
__global__ __launch_bounds__(512, 2) void ffn2(
    const unsigned short* __restrict__ xbf,
    const unsigned short* __restrict__ W1s,
    const unsigned short* __restrict__ W2s,
    const int* __restrict__ counts, const int* __restrict__ tokl,
    const float* __restrict__ wgtl, float* __restrict__ out) {
  int id = blockIdx.x;
  // XCD-clustered mapping: expert e lives entirely on XCD e>>1
  int e = ((id & 7) << 1) | ((id >> 3) & 1);
  int tile = id >> 4;                       // 0..127
  int cnt = counts[e];
  int base = tile * 64;
  if (base >= cnt) return;
  int m = min(64, cnt - base);

  extern __shared__ char smem[];
  char* xs = smem + F2_XS;
  char* uts = smem + F2_UT;
  int* tks = (int*)(smem + F2_TK);
  float* wgs = (float*)(smem + F2_WG);

  int tid = threadIdx.x, wid = tid >> 6, lane = tid & 63;
  int llo = lane & 15, lhi = lane >> 4;

  if (tid < 64) {
    int tk = 0; float w = 0.f;
    if (tid < m) { tk = tokl[e * NTOK + base + tid]; w = wgtl[e * NTOK + base + tid]; }
    tks[tid] = tk; wgs[tid] = w;
  }
  __syncthreads();

  // ---- stage whole X tile [64][1024] bf16, swizzle baked into source addr ----
  // LDS position p (16B units within row) holds logical k-oct p^(r&7).
#pragma unroll
  for (int i = 0; i < 16; ++i) {
    int chunk = wid * 16 + i;               // 128 chunks of 1 KB
    int r = chunk >> 1;
    int pos = ((chunk & 1) << 6) | lane;    // 0..127
    const unsigned short* src =
        xbf + ((size_t)tks[r] << 10) + ((pos ^ (r & 7)) << 3);
    gld_lds16(src, xs + (chunk << 10));
  }
  __syncthreads();

  const unsigned short* w1e = W1s + ((size_t)e << 21);
  const unsigned short* w2e = W2s + ((size_t)e << 21);
  const int fw = wid >> 1;                  // GEMM1 f-group (0..3), 32 f each
  const int rwb = (wid & 1) * 32;           // GEMM1 r-group base
  const int cwb = wid * 128;                // GEMM2 c-range base

  f32x4 acc[4][8];
#pragma unroll
  for (int i = 0; i < 4; ++i)
#pragma unroll
    for (int j = 0; j < 8; ++j) acc[i][j] = (f32x4){0.f, 0.f, 0.f, 0.f};

  const int r0 = rwb + llo, r1 = rwb + 16 + llo;
  const int sw0 = r0 & 7, sw1 = r1 & 7;

  for (int fci = 0; fci < 16; ++fci) {
    // ================= GEMM1 (swapped): U'[f][r], f-chunk = fci*128 =================
    f32x4 acc1[2][2];
#pragma unroll
    for (int i = 0; i < 2; ++i)
#pragma unroll
      for (int j = 0; j < 2; ++j) acc1[i][j] = (f32x4){0.f, 0.f, 0.f, 0.f};

    const unsigned short* w1p =
        w1e + ((size_t)(fci * 8 + fw * 2) << 14);   // *32 chunks *512
#pragma unroll 4
    for (int kk = 0; kk < 32; ++kk) {
      bf16x8 af0 = *(const bf16x8*)(w1p + ((size_t)kk << 9) + lane * 8);
      bf16x8 af1 = *(const bf16x8*)(w1p + ((size_t)(32 + kk) << 9) + lane * 8);
      int jo = (kk << 2) + lhi;
      bf16x8 bx0 = *(const bf16x8*)(xs + (r0 << 11) + ((jo ^ sw0) << 4));
      bf16x8 bx1 = *(const bf16x8*)(xs + (r1 << 11) + ((jo ^ sw1) << 4));
      acc1[0][0] = __builtin_amdgcn_mfma_f32_16x16x32_bf16(af0, bx0, acc1[0][0], 0, 0, 0);
      acc1[0][1] = __builtin_amdgcn_mfma_f32_16x16x32_bf16(af0, bx1, acc1[0][1], 0, 0, 0);
      acc1[1][0] = __builtin_amdgcn_mfma_f32_16x16x32_bf16(af1, bx0, acc1[1][0], 0, 0, 0);
      acc1[1][1] = __builtin_amdgcn_mfma_f32_16x16x32_bf16(af1, bx1, acc1[1][1], 0, 0, 0);
    }
    // silu -> U LDS [64 r][128 f'] swizzled
#pragma unroll
    for (int fi = 0; fi < 2; ++fi)
#pragma unroll
      for (int ri = 0; ri < 2; ++ri) {
        int r = rwb + ri * 16 + llo;
        int fb = fw * 32 + fi * 16 + lhi * 4;
        float u0 = silu_f(acc1[fi][ri][0]);
        float u1 = silu_f(acc1[fi][ri][1]);
        float u2 = silu_f(acc1[fi][ri][2]);
        float u3 = silu_f(acc1[fi][ri][3]);
        uint2 pv; pv.x = pk2(u0, u1); pv.y = pk2(u2, u3);
        *(uint2*)(uts + (r << 8) + (((fb >> 3) ^ (r & 7)) << 4) + ((fb & 7) << 1)) = pv;
      }
    __syncthreads();

    // ================= GEMM2: Y[64][1024] += U[64][128] @ W2[128][1024] =================
    const unsigned short* w2p = w2e + ((size_t)fci << 17);   // kk2 base = fci*4, *64*512
#pragma unroll 2
    for (int ks = 0; ks < 4; ++ks) {
      bf16x8 bw[8];
#pragma unroll
      for (int ci = 0; ci < 8; ++ci)
        bw[ci] = *(const bf16x8*)(w2p + ((size_t)(ks * 64 + wid * 8 + ci) << 9) + lane * 8);
      bf16x8 au[4];
#pragma unroll
      for (int ri = 0; ri < 4; ++ri) {
        int r = ri * 16 + llo;
        int po = (ks << 2) + lhi;
        au[ri] = *(const bf16x8*)(uts + (r << 8) + ((po ^ (r & 7)) << 4));
      }
#pragma unroll
      for (int ri = 0; ri < 4; ++ri)
#pragma unroll
        for (int ci = 0; ci < 8; ++ci)
          acc[ri][ci] = __builtin_amdgcn_mfma_f32_16x16x32_bf16(au[ri], bw[ci], acc[ri][ci], 0, 0, 0);
    }
    __syncthreads();
  }

  // epilogue: y[tok[r]][c] += w[r] * acc
#pragma unroll
  for (int ri = 0; ri < 4; ++ri)
#pragma unroll
    for (int reg = 0; reg < 4; ++reg) {
      int r = ri * 16 + 4 * lhi + reg;
      if (r < m) {
        float w = wgs[r];
        size_t orow = (size_t)tks[r] * DDIM;
#pragma unroll
        for (int ci = 0; ci < 8; ++ci)
          atomicAdd(&out[orow + cwb + ci * 16 + llo], acc[ri][ci][reg] * w);
      }
    }
}

// ---------------- fallback (round-1) fused FFN ----------------
__global__ __launch_bounds__(512, 2) void ffn_kernel(
    const float* __restrict__ x, const float* __restrict__ W1,
    const float* __restrict__ W2, const int* __restrict__ counts,
    const int* __restrict__ tokl, const float* __restrict__ wgtl,
    float* __restrict__ out) {
  int e = blockIdx.y;
  int cnt = counts[e];
  int base = blockIdx.x * 64;
  if (base >= cnt) return;
  int m = min(64, cnt - base);

  extern __shared__ char smem[];
  unsigned short* xs  = (unsigned short*)(smem + SM_XS);
  unsigned short* w1t = (unsigned short*)(smem + SM_W1);
  unsigned short* ut  = (unsigned short*)(smem + SM_UT);
  unsigned short* w2t = (unsigned short*)(smem + SM_W2);
  int*   tks = (int*)(smem + SM_TK);
  float* wgs = (float*)(smem + SM_WG);

  int tid = threadIdx.x;
  int wid = tid >> 6;
  int lane = tid & 63;
  int lhi = lane >> 4;
  int llo = lane & 15;

  if (tid < 64) {
    int tk = 0; float w = 0.f;
    if (tid < m) { tk = tokl[e * NTOK + base + tid]; w = wgtl[e * NTOK + base + tid]; }
    tks[tid] = tk; wgs[tid] = w;
  }
  __syncthreads();

  const float* W1e = W1 + (size_t)e * DDIM * FDIM;
  const float* W2e = W2 + (size_t)e * FDIM * DDIM;

  const int fwb = (wid >> 1) * 64;
  const int rwb = (wid & 1) * 32;
  const int cwb = wid * 128;

  f32x4 acc[4][8];
#pragma unroll
  for (int i = 0; i < 4; ++i)
#pragma unroll
    for (int j = 0; j < 8; ++j) acc[i][j] = (f32x4){0.f, 0.f, 0.f, 0.f};

  for (int fc = 0; fc < FDIM; fc += 256) {
    f32x4 acc1[4][2];
#pragma unroll
    for (int i = 0; i < 4; ++i)
#pragma unroll
      for (int j = 0; j < 2; ++j) acc1[i][j] = (f32x4){0.f, 0.f, 0.f, 0.f};

    for (int kc = 0; kc < DDIM; kc += 64) {
      __syncthreads();
      {
        int r = tid >> 3, ko = tid & 7;
        float4 v0, v1;
        if (r < m) {
          const float* p = x + (size_t)tks[r] * DDIM + kc + ko * 8;
          v0 = *(const float4*)p; v1 = *(const float4*)(p + 4);
        } else {
          v0 = make_float4(0.f, 0.f, 0.f, 0.f); v1 = v0;
        }
        uint4 pk;
        pk.x = pk2(v0.x, v0.y); pk.y = pk2(v0.z, v0.w);
        pk.z = pk2(v1.x, v1.y); pk.w = pk2(v1.z, v1.w);
        *(uint4*)&xs[r * 72 + ko * 8] = pk;
      }
#pragma unroll
      for (int it = 0; it < 2; ++it) {
        int task = tid + 512 * it;
        int kp = task & 31, fo = task >> 5;
        const float* p0 = W1e + (size_t)(kc + kp * 2) * FDIM + fc + fo * 8;
        const float* p1 = p0 + FDIM;
        float4 a0 = *(const float4*)p0, a1 = *(const float4*)(p0 + 4);
        float4 b0 = *(const float4*)p1, b1 = *(const float4*)(p1 + 4);
        float av[8] = {a0.x,a0.y,a0.z,a0.w,a1.x,a1.y,a1.z,a1.w};
        float bv[8] = {b0.x,b0.y,b0.z,b0.w,b1.x,b1.y,b1.z,b1.w};
#pragma unroll
        for (int j = 0; j < 8; ++j)
          *(unsigned int*)&w1t[(size_t)(fo * 8 + j) * 72 + kp * 2] = pk2(av[j], bv[j]);
      }
      __syncthreads();
#pragma unroll
      for (int ks = 0; ks < 64; ks += 32) {
        bf16x8 af[4], bx[2];
#pragma unroll
        for (int fi = 0; fi < 4; ++fi)
          af[fi] = *(const bf16x8*)&w1t[(size_t)(fwb + fi * 16 + llo) * 72 + ks + lhi * 8];
#pragma unroll
        for (int ri = 0; ri < 2; ++ri)
          bx[ri] = *(const bf16x8*)&xs[(size_t)(rwb + ri * 16 + llo) * 72 + ks + lhi * 8];
#pragma unroll
        for (int fi = 0; fi < 4; ++fi)
#pragma unroll
          for (int ri = 0; ri < 2; ++ri)
            acc1[fi][ri] = __builtin_amdgcn_mfma_f32_16x16x32_bf16(
                af[fi], bx[ri], acc1[fi][ri], 0, 0, 0);
      }
    }
#pragma unroll
    for (int fi = 0; fi < 4; ++fi)
#pragma unroll
      for (int ri = 0; ri < 2; ++ri) {
        int r  = rwb + ri * 16 + llo;
        int fb = fwb + fi * 16 + 4 * lhi;
        float u0 = silu_f(acc1[fi][ri][0]);
        float u1 = silu_f(acc1[fi][ri][1]);
        float u2 = silu_f(acc1[fi][ri][2]);
        float u3 = silu_f(acc1[fi][ri][3]);
        uint2 pv; pv.x = pk2(u0, u1); pv.y = pk2(u2, u3);
        *(uint2*)&ut[(size_t)r * 264 + fb] = pv;
      }
    __syncthreads();

    for (int kc2 = 0; kc2 < 256; kc2 += 32) {
#pragma unroll
      for (int it = 0; it < 4; ++it) {
        int task = tid + 512 * it;
        int kp = task & 15, co = task >> 4;
        const float* p0 = W2e + (size_t)(fc + kc2 + kp * 2) * DDIM + co * 8;
        const float* p1 = p0 + DDIM;
        float4 a0 = *(const float4*)p0, a1 = *(const float4*)(p0 + 4);
        float4 b0 = *(const float4*)p1, b1 = *(const float4*)(p1 + 4);
        float av[8] = {a0.x,a0.y,a0.z,a0.w,a1.x,a1.y,a1.z,a1.w};
        float bv[8] = {b0.x,b0.y,b0.z,b0.w,b1.x,b1.y,b1.z,b1.w};
#pragma unroll
        for (int j = 0; j < 8; ++j)
          *(unsigned int*)&w2t[(size_t)(co * 8 + j) * 40 + kp * 2] = pk2(av[j], bv[j]);
      }
      __syncthreads();
      bf16x8 au[4], bw[8];
#pragma unroll
      for (int ri = 0; ri < 4; ++ri)
        au[ri] = *(const bf16x8*)&ut[(size_t)(ri * 16 + llo) * 264 + kc2 + lhi * 8];
#pragma unroll
      for (int ci = 0; ci < 8; ++ci)
        bw[ci] = *(const bf16x8*)&w2t[(size_t)(cwb + ci * 16 + llo) * 40 + lhi * 8];
#pragma unroll
      for (int ri = 0; ri < 4; ++ri)
#pragma unroll
        for (int ci = 0; ci < 8; ++ci)
          acc[ri][ci] = __builtin_amdgcn_mfma_f32_16x16x32_bf16(
              au[ri], bw[ci], acc[ri][ci], 0, 0, 0);
      __syncthreads();
    }
  }

#pragma unroll
  for (int ri = 0; ri < 4; ++ri)
#pragma unroll
    for (int reg = 0; reg < 4; ++reg) {
      int r = ri * 16 + 4 * lhi + reg;
      if (r < m) {
        float w = wgs[r];
        size_t orow = (size_t)tks[r] * DDIM;
#pragma unroll
        for (int ci = 0; ci < 8; ++ci)
          atomicAdd(&out[orow + cwb + ci * 16 + llo], acc[ri][ci][reg] * w);
      }
    }
}

extern "C" void kernel_launch(void* const* d_in, const int* in_sizes, int n_in,
                              void* d_out, int out_size, void* d_ws, size_t ws_size,
                              hipStream_t stream) {
  const float* x  = (const float*)d_in[0];
  const float* Wg = (const float*)d_in[1];
  const float* W1 = (const float*)d_in[2];
  const float* W2 = (const float*)d_in[3];
  float* out = (float*)d_out;

  int*   counts = (int*)((char*)d_ws + WS_COUNTS);
  int*   tokl   = (int*)((char*)d_ws + WS_TOKL);
  float* wgtl   = (float*)((char*)d_ws + WS_WGTL);

  hipMemsetAsync(counts, 0, 256, stream);
  hipMemsetAsync(d_out, 0, (size_t)out_size * sizeof(float), stream);

  gate_kernel<<<NTOK / 4, 256, 0, stream>>>(x, Wg, counts, tokl, wgtl);

  if (ws_size >= WS_NEED) {
    unsigned short* xbf = (unsigned short*)((char*)d_ws + WS_XBF);
    unsigned short* W1s = (unsigned short*)((char*)d_ws + WS_W1S);
    unsigned short* W2s = (unsigned short*)((char*)d_ws + WS_W2S);
    convert_x<<<4096, 512, 0, stream>>>(x, xbf);
    convert_w<<<16384, 512, 0, stream>>>(W1, W2, W1s, W2s);
    hipFuncSetAttribute((const void*)ffn2,
                        hipFuncAttributeMaxDynamicSharedMemorySize, F2_TOTAL);
    ffn2<<<2048, 512, F2_TOTAL, stream>>>(xbf, W1s, W2s, counts, tokl, wgtl, out);
  } else {
    hipFuncSetAttribute((const void*)ffn_kernel,
                        hipFuncAttributeMaxDynamicSharedMemorySize, SM_TOTAL);
    dim3 g(NTOK / 64, NEXP);
    ffn_kernel<<<g, 512, SM_TOTAL, stream>>>(x, W1, W2, counts, tokl, wgtl, out);
  }
}

// Round 3
// 835.416 us; speedup vs baseline: 2.0350x; 1.4009x over previous
//
#include <hip/hip_runtime.h>
#include <hip/hip_bf16.h>

#define NTOK 8192   // B*T tokens
#define DDIM 1024
#define FDIM 2048
#define NEXP 16

// ---------------- workspace layout (bytes) ----------------
#define WS_COUNTS 0
#define WS_TOKL   4096
#define WS_WGTL   (4096 + NTOK*NEXP*4)
#define WS_XBF    (size_t)(2u<<20)    // 16 MiB bf16 x
#define WS_W1S    (size_t)(32u<<20)   // 64 MiB bf16 W1 frag-ordered
#define WS_W2S    (size_t)(96u<<20)   // 64 MiB bf16 W2 frag-ordered
#define WS_NEED   (size_t)(160u<<20)

// ---------------- ffn3 LDS layout (bytes) ----------------
#define F3_XS 0          // [64][1024] bf16, rows 2048 B, 16B-slot XOR swizzle
#define F3_UT 131072     // [64][128]  bf16, rows 256 B, swizzled
#define F3_TK 147456     // int[64]
#define F3_WG 147712     // float[64]
#define F3_TOTAL 147968

// ---------------- old (fallback) ffn LDS layout ----------------
#define SM_XS 0
#define SM_W1 9216
#define SM_UT 46080
#define SM_W2 79872
#define SM_TK 161792
#define SM_WG 162048
#define SM_TOTAL 162304

typedef short bf16x8 __attribute__((ext_vector_type(8)));
typedef float f32x4  __attribute__((ext_vector_type(4)));

__device__ __forceinline__ unsigned short f2bf(float f) {
  unsigned int u = __builtin_bit_cast(unsigned int, f);
  u += 0x7fffu + ((u >> 16) & 1u);            // RNE
  return (unsigned short)(u >> 16);
}
__device__ __forceinline__ unsigned int pk2(float a, float b) {
  return (unsigned int)f2bf(a) | ((unsigned int)f2bf(b) << 16);
}
__device__ __forceinline__ float silu_f(float s) {
  return s / (1.f + __expf(-s));
}
__device__ __forceinline__ void gld_lds16(const void* g, void* l) {
  __builtin_amdgcn_global_load_lds((const __attribute__((address_space(1))) void*)g,
                                   (__attribute__((address_space(3))) void*)l, 16, 0, 0);
}

// ---------------- gate: logits -> top2 -> softmax -> per-expert lists ----------------
__global__ __launch_bounds__(256) void gate_kernel(
    const float* __restrict__ x, const float* __restrict__ Wg,
    int* __restrict__ counts, int* __restrict__ tokl, float* __restrict__ wgtl) {
  int gtid = blockIdx.x * blockDim.x + threadIdx.x;
  int tok = gtid >> 6;
  int lane = threadIdx.x & 63;
  if (tok >= NTOK) return;
  const float* xr = x + (size_t)tok * DDIM;
  float xv[16];
#pragma unroll
  for (int j = 0; j < 16; ++j) xv[j] = xr[lane + 64 * j];
  float lg[NEXP];
#pragma unroll
  for (int e = 0; e < NEXP; ++e) {
    float s = 0.f;
#pragma unroll
    for (int j = 0; j < 16; ++j) s += xv[j] * Wg[(lane + 64 * j) * NEXP + e];
#pragma unroll
    for (int off = 32; off > 0; off >>= 1) s += __shfl_xor(s, off);
    lg[e] = s;
  }
  int e0 = 0; float b0 = lg[0];
#pragma unroll
  for (int e = 1; e < NEXP; ++e) if (lg[e] > b0) { b0 = lg[e]; e0 = e; }
  int e1 = -1; float b1 = -3.4e38f;
#pragma unroll
  for (int e = 0; e < NEXP; ++e) if (e != e0 && lg[e] > b1) { b1 = lg[e]; e1 = e; }
  float t = expf(b1 - b0);
  float w0 = 1.f / (1.f + t);
  float w1 = t / (1.f + t);
  if (lane == 0) {
    int p = atomicAdd(&counts[e0], 1);
    tokl[e0 * NTOK + p] = tok; wgtl[e0 * NTOK + p] = w0;
    p = atomicAdd(&counts[e1], 1);
    tokl[e1 * NTOK + p] = tok; wgtl[e1 * NTOK + p] = w1;
  }
}

// ---------------- x fp32 -> bf16 row-major ----------------
__global__ __launch_bounds__(512) void convert_x(const float* __restrict__ x,
                                                 unsigned short* __restrict__ xbf) {
  int i = blockIdx.x * 512 + threadIdx.x;   // over 2,097,152 float4s (exact)
  float4 v = ((const float4*)x)[i];
  uint2 o; o.x = pk2(v.x, v.y); o.y = pk2(v.z, v.w);
  ((uint2*)xbf)[i] = o;
}

// ---------------- W1/W2 fp32 -> bf16, MFMA-fragment-ordered ----------------
// W1s chunk gid = (e*128 + ff)*32 + kk : 512 elems; lane(llo,lhi), j:
//   val = bf16(W1[e][kk*32+lhi*8+j][ff*16+llo])
// W2s chunk g   = (e*64 + kk)*64 + cc :
//   val = bf16(W2[e][kk*32+lhi*8+j][cc*16+llo])
__global__ __launch_bounds__(512) void convert_w(
    const float* __restrict__ W1, const float* __restrict__ W2,
    unsigned short* __restrict__ W1s, unsigned short* __restrict__ W2s) {
  int gid = blockIdx.x * 8 + (threadIdx.x >> 6);
  int lane = threadIdx.x & 63, llo = lane & 15, lhi = lane >> 4;
  const float* src;
  unsigned short* dst;
  int C;
  if (gid < 65536) {
    int e = gid >> 12, ff = (gid >> 5) & 127, kk = gid & 31;
    src = W1 + ((size_t)e << 21) + (size_t)(kk * 32 + lhi * 8) * FDIM + ff * 16 + llo;
    dst = W1s + ((size_t)gid << 9) + lane * 8;
    C = FDIM;
  } else {
    int g = gid - 65536;
    int e = g >> 12, kk = (g >> 6) & 63, cc = g & 63;
    src = W2 + ((size_t)e << 21) + (size_t)(kk * 32 + lhi * 8) * DDIM + cc * 16 + llo;
    dst = W2s + ((size_t)g << 9) + lane * 8;
    C = DDIM;
  }
  float v[8];
#pragma unroll
  for (int j = 0; j < 8; ++j) v[j] = src[(size_t)j * C];
  uint4 o;
  o.x = pk2(v[0], v[1]); o.y = pk2(v[2], v[3]);
  o.z = pk2(v[4], v[5]); o.w = pk2(v[6], v[7]);
  *(uint4*)dst = o;
}

// ---------------- fused FFN v3: 16 waves, rotated weight prefetch, raw barriers ----------------
__global__ __launch_bounds__(1024, 4) void ffn3(
    const unsigned short* __restrict__ xbf,
    const unsigned short* __restrict__ W1s,
    const unsigned short* __restrict__ W2s,
    const int* __restrict__ counts, const int* __restrict__ tokl,
    const float* __restrict__ wgtl, float* __restrict__ out) {
  int id = blockIdx.x;
  // XCD-clustered mapping: expert e lives entirely on XCD e>>1
  int e = ((id & 7) << 1) | ((id >> 3) & 1);
  int tile = id >> 4;                       // 0..127
  int cnt = counts[e];
  int base = tile * 64;
  if (base >= cnt) return;
  int m = min(64, cnt - base);

  extern __shared__ char smem[];
  char* xs = smem + F3_XS;
  char* uts = smem + F3_UT;
  int* tks = (int*)(smem + F3_TK);
  float* wgs = (float*)(smem + F3_WG);

  int tid = threadIdx.x, wid = tid >> 6, lane = tid & 63;
  int llo = lane & 15, lhi = lane >> 4;

  if (tid < 64) {
    int tk = 0; float w = 0.f;
    if (tid < m) { tk = tokl[e * NTOK + base + tid]; w = wgtl[e * NTOK + base + tid]; }
    tks[tid] = tk; wgs[tid] = w;
  }
  __syncthreads();

  // ---- stage whole X tile [64][1024] bf16, swizzle baked into source addr ----
  // LDS position p (16B units within row) holds logical k-oct p^(r&7).
#pragma unroll
  for (int i = 0; i < 8; ++i) {
    int chunk = wid * 8 + i;                // 128 chunks of 1 KB
    int r = chunk >> 1;
    int pos = ((chunk & 1) << 6) | lane;    // 0..127
    const unsigned short* src =
        xbf + ((size_t)tks[r] << 10) + ((pos ^ (r & 7)) << 3);
    gld_lds16(src, xs + (chunk << 10));
  }
  __syncthreads();

  const unsigned short* w1e = W1s + ((size_t)e << 21);
  const unsigned short* w2e = W2s + ((size_t)e << 21);
  const int fw = wid >> 1;                  // GEMM1 f-group (0..7), 16 f each
  const int rwb = (wid & 1) * 32;           // GEMM1 r-group base
  const int cwb = wid * 64;                 // GEMM2 c-range base (16 x 64)

  f32x4 acc[4][4];
#pragma unroll
  for (int i = 0; i < 4; ++i)
#pragma unroll
    for (int j = 0; j < 4; ++j) acc[i][j] = (f32x4){0.f, 0.f, 0.f, 0.f};

  const int r0 = rwb + llo, r1 = r0 + 16;
  const int sw0 = r0 & 7;                   // note (r1 & 7) == sw0

  // prologue: preload first fci's W1 fragments (4-deep)
  bf16x8 afc[4];
  {
    const unsigned short* w1p = w1e + ((size_t)fw << 14);
#pragma unroll
    for (int j = 0; j < 4; ++j)
      afc[j] = *(const bf16x8*)(w1p + (j << 9) + lane * 8);
  }

  for (int fci = 0; fci < 16; ++fci) {
    // ================= GEMM1 (swapped): U'[16 f][32 r] per wave =================
    const unsigned short* w1p = w1e + ((size_t)(fci * 8 + fw) << 14);
    f32x4 acc1[2];
    acc1[0] = (f32x4){0.f, 0.f, 0.f, 0.f};
    acc1[1] = (f32x4){0.f, 0.f, 0.f, 0.f};
#pragma unroll
    for (int kk4 = 0; kk4 < 8; ++kk4) {
      bf16x8 afn[4];
      if (kk4 < 7) {
#pragma unroll
        for (int j = 0; j < 4; ++j)
          afn[j] = *(const bf16x8*)(w1p + ((kk4 * 4 + 4 + j) << 9) + lane * 8);
      }
#pragma unroll
      for (int j = 0; j < 4; ++j) {
        int jo = ((kk4 * 4 + j) << 2) + lhi;
        bf16x8 bx0 = *(const bf16x8*)(xs + (r0 << 11) + ((jo ^ sw0) << 4));
        bf16x8 bx1 = *(const bf16x8*)(xs + (r1 << 11) + ((jo ^ sw0) << 4));
        acc1[0] = __builtin_amdgcn_mfma_f32_16x16x32_bf16(afc[j], bx0, acc1[0], 0, 0, 0);
        acc1[1] = __builtin_amdgcn_mfma_f32_16x16x32_bf16(afc[j], bx1, acc1[1], 0, 0, 0);
      }
      if (kk4 < 7) {
#pragma unroll
        for (int j = 0; j < 4; ++j) afc[j] = afn[j];
      }
    }
    // silu -> U LDS [64 r][128 f'] swizzled
#pragma unroll
    for (int ri = 0; ri < 2; ++ri) {
      int r = rwb + ri * 16 + llo;
      int fb = fw * 16 + lhi * 4;
      float u0 = silu_f(acc1[ri][0]);
      float u1 = silu_f(acc1[ri][1]);
      float u2 = silu_f(acc1[ri][2]);
      float u3 = silu_f(acc1[ri][3]);
      uint2 pv; pv.x = pk2(u0, u1); pv.y = pk2(u2, u3);
      *(uint2*)(uts + (r << 8) + (((fb >> 3) ^ (r & 7)) << 4) + ((fb & 7) << 1)) = pv;
    }
    // preload GEMM2's first W2 fragments before the barrier (stays in flight)
    bf16x8 bwc[4];
    {
      const unsigned short* w2p = w2e + ((size_t)((fci * 4) * 64 + wid * 4) << 9);
#pragma unroll
      for (int ci = 0; ci < 4; ++ci)
        bwc[ci] = *(const bf16x8*)(w2p + (ci << 9) + lane * 8);
    }
    asm volatile("s_waitcnt lgkmcnt(0)" ::: "memory");  // U writes visible
    __builtin_amdgcn_s_barrier();

    // ================= GEMM2: Y[64][1024] += U[64][128] @ W2[128][1024] =================
#pragma unroll
    for (int ks = 0; ks < 4; ++ks) {
      bf16x8 bwn[4];
      if (ks < 3) {
        const unsigned short* w2q =
            w2e + ((size_t)((fci * 4 + ks + 1) * 64 + wid * 4) << 9);
#pragma unroll
        for (int ci = 0; ci < 4; ++ci)
          bwn[ci] = *(const bf16x8*)(w2q + (ci << 9) + lane * 8);
      }
      bf16x8 au[4];
#pragma unroll
      for (int ri = 0; ri < 4; ++ri) {
        int r = ri * 16 + llo;
        int po = (ks << 2) + lhi;
        au[ri] = *(const bf16x8*)(uts + (r << 8) + ((po ^ (r & 7)) << 4));
      }
#pragma unroll
      for (int ri = 0; ri < 4; ++ri)
#pragma unroll
        for (int ci = 0; ci < 4; ++ci)
          acc[ri][ci] = __builtin_amdgcn_mfma_f32_16x16x32_bf16(au[ri], bwc[ci], acc[ri][ci], 0, 0, 0);
      if (ks < 3) {
#pragma unroll
        for (int ci = 0; ci < 4; ++ci) bwc[ci] = bwn[ci];
      }
    }
    // preload next fci's W1 fragments before the barrier
    if (fci < 15) {
      const unsigned short* w1n = w1e + ((size_t)((fci + 1) * 8 + fw) << 14);
#pragma unroll
      for (int j = 0; j < 4; ++j)
        afc[j] = *(const bf16x8*)(w1n + (j << 9) + lane * 8);
    }
    asm volatile("s_waitcnt lgkmcnt(0)" ::: "memory");  // U reads done
    __builtin_amdgcn_s_barrier();
  }

  // epilogue: y[tok[r]][c] += w[r] * acc
#pragma unroll
  for (int ri = 0; ri < 4; ++ri)
#pragma unroll
    for (int reg = 0; reg < 4; ++reg) {
      int r = ri * 16 + 4 * lhi + reg;
      if (r < m) {
        float w = wgs[r];
        size_t orow = (size_t)tks[r] * DDIM;
#pragma unroll
        for (int ci = 0; ci < 4; ++ci)
          atomicAdd(&out[orow + cwb + ci * 16 + llo], acc[ri][ci][reg] * w);
      }
    }
}

// ---------------- fallback (round-1) fused FFN ----------------
__global__ __launch_bounds__(512, 2) void ffn_kernel(
    const float* __restrict__ x, const float* __restrict__ W1,
    const float* __restrict__ W2, const int* __restrict__ counts,
    const int* __restrict__ tokl, const float* __restrict__ wgtl,
    float* __restrict__ out) {
  int e = blockIdx.y;
  int cnt = counts[e];
  int base = blockIdx.x * 64;
  if (base >= cnt) return;
  int m = min(64, cnt - base);

  extern __shared__ char smem[];
  unsigned short* xs  = (unsigned short*)(smem + SM_XS);
  unsigned short* w1t = (unsigned short*)(smem + SM_W1);
  unsigned short* ut  = (unsigned short*)(smem + SM_UT);
  unsigned short* w2t = (unsigned short*)(smem + SM_W2);
  int*   tks = (int*)(smem + SM_TK);
  float* wgs = (float*)(smem + SM_WG);

  int tid = threadIdx.x;
  int wid = tid >> 6;
  int lane = tid & 63;
  int lhi = lane >> 4;
  int llo = lane & 15;

  if (tid < 64) {
    int tk = 0; float w = 0.f;
    if (tid < m) { tk = tokl[e * NTOK + base + tid]; w = wgtl[e * NTOK + base + tid]; }
    tks[tid] = tk; wgs[tid] = w;
  }
  __syncthreads();

  const float* W1e = W1 + (size_t)e * DDIM * FDIM;
  const float* W2e = W2 + (size_t)e * FDIM * DDIM;

  const int fwb = (wid >> 1) * 64;
  const int rwb = (wid & 1) * 32;
  const int cwb = wid * 128;

  f32x4 acc[4][8];
#pragma unroll
  for (int i = 0; i < 4; ++i)
#pragma unroll
    for (int j = 0; j < 8; ++j) acc[i][j] = (f32x4){0.f, 0.f, 0.f, 0.f};

  for (int fc = 0; fc < FDIM; fc += 256) {
    f32x4 acc1[4][2];
#pragma unroll
    for (int i = 0; i < 4; ++i)
#pragma unroll
      for (int j = 0; j < 2; ++j) acc1[i][j] = (f32x4){0.f, 0.f, 0.f, 0.f};

    for (int kc = 0; kc < DDIM; kc += 64) {
      __syncthreads();
      {
        int r = tid >> 3, ko = tid & 7;
        float4 v0, v1;
        if (r < m) {
          const float* p = x + (size_t)tks[r] * DDIM + kc + ko * 8;
          v0 = *(const float4*)p; v1 = *(const float4*)(p + 4);
        } else {
          v0 = make_float4(0.f, 0.f, 0.f, 0.f); v1 = v0;
        }
        uint4 pk;
        pk.x = pk2(v0.x, v0.y); pk.y = pk2(v0.z, v0.w);
        pk.z = pk2(v1.x, v1.y); pk.w = pk2(v1.z, v1.w);
        *(uint4*)&xs[r * 72 + ko * 8] = pk;
      }
#pragma unroll
      for (int it = 0; it < 2; ++it) {
        int task = tid + 512 * it;
        int kp = task & 31, fo = task >> 5;
        const float* p0 = W1e + (size_t)(kc + kp * 2) * FDIM + fc + fo * 8;
        const float* p1 = p0 + FDIM;
        float4 a0 = *(const float4*)p0, a1 = *(const float4*)(p0 + 4);
        float4 b0 = *(const float4*)p1, b1 = *(const float4*)(p1 + 4);
        float av[8] = {a0.x,a0.y,a0.z,a0.w,a1.x,a1.y,a1.z,a1.w};
        float bv[8] = {b0.x,b0.y,b0.z,b0.w,b1.x,b1.y,b1.z,b1.w};
#pragma unroll
        for (int j = 0; j < 8; ++j)
          *(unsigned int*)&w1t[(size_t)(fo * 8 + j) * 72 + kp * 2] = pk2(av[j], bv[j]);
      }
      __syncthreads();
#pragma unroll
      for (int ks = 0; ks < 64; ks += 32) {
        bf16x8 af[4], bx[2];
#pragma unroll
        for (int fi = 0; fi < 4; ++fi)
          af[fi] = *(const bf16x8*)&w1t[(size_t)(fwb + fi * 16 + llo) * 72 + ks + lhi * 8];
#pragma unroll
        for (int ri = 0; ri < 2; ++ri)
          bx[ri] = *(const bf16x8*)&xs[(size_t)(rwb + ri * 16 + llo) * 72 + ks + lhi * 8];
#pragma unroll
        for (int fi = 0; fi < 4; ++fi)
#pragma unroll
          for (int ri = 0; ri < 2; ++ri)
            acc1[fi][ri] = __builtin_amdgcn_mfma_f32_16x16x32_bf16(
                af[fi], bx[ri], acc1[fi][ri], 0, 0, 0);
      }
    }
#pragma unroll
    for (int fi = 0; fi < 4; ++fi)
#pragma unroll
      for (int ri = 0; ri < 2; ++ri) {
        int r  = rwb + ri * 16 + llo;
        int fb = fwb + fi * 16 + 4 * lhi;
        float u0 = silu_f(acc1[fi][ri][0]);
        float u1 = silu_f(acc1[fi][ri][1]);
        float u2 = silu_f(acc1[fi][ri][2]);
        float u3 = silu_f(acc1[fi][ri][3]);
        uint2 pv; pv.x = pk2(u0, u1); pv.y = pk2(u2, u3);
        *(uint2*)&ut[(size_t)r * 264 + fb] = pv;
      }
    __syncthreads();

    for (int kc2 = 0; kc2 < 256; kc2 += 32) {
#pragma unroll
      for (int it = 0; it < 4; ++it) {
        int task = tid + 512 * it;
        int kp = task & 15, co = task >> 4;
        const float* p0 = W2e + (size_t)(fc + kc2 + kp * 2) * DDIM + co * 8;
        const float* p1 = p0 + DDIM;
        float4 a0 = *(const float4*)p0, a1 = *(const float4*)(p0 + 4);
        float4 b0 = *(const float4*)p1, b1 = *(const float4*)(p1 + 4);
        float av[8] = {a0.x,a0.y,a0.z,a0.w,a1.x,a1.y,a1.z,a1.w};
        float bv[8] = {b0.x,b0.y,b0.z,b0.w,b1.x,b1.y,b1.z,b1.w};
#pragma unroll
        for (int j = 0; j < 8; ++j)
          *(unsigned int*)&w2t[(size_t)(co * 8 + j) * 40 + kp * 2] = pk2(av[j], bv[j]);
      }
      __syncthreads();
      bf16x8 au[4], bw[8];
#pragma unroll
      for (int ri = 0; ri < 4; ++ri)
        au[ri] = *(const bf16x8*)&ut[(size_t)(ri * 16 + llo) * 264 + kc2 + lhi * 8];
#pragma unroll
      for (int ci = 0; ci < 8; ++ci)
        bw[ci] = *(const bf16x8*)&w2t[(size_t)(cwb + ci * 16 + llo) * 40 + lhi * 8];
#pragma unroll
      for (int ri = 0; ri < 4; ++ri)
#pragma unroll
        for (int ci = 0; ci < 8; ++ci)
          acc[ri][ci] = __builtin_amdgcn_mfma_f32_16x16x32_bf16(
              au[ri], bw[ci], acc[ri][ci], 0, 0, 0);
      __syncthreads();
    }
  }

#pragma unroll
  for (int ri = 0; ri < 4; ++ri)
#pragma unroll
    for (int reg = 0; reg < 4; ++reg) {
      int r = ri * 16 + 4 * lhi + reg;
      if (r < m) {
        float w = wgs[r];
        size_t orow = (size_t)tks[r] * DDIM;
#pragma unroll
        for (int ci = 0; ci < 8; ++ci)
          atomicAdd(&out[orow + cwb + ci * 16 + llo], acc[ri][ci][reg] * w);
      }
    }
}

extern "C" void kernel_launch(void* const* d_in, const int* in_sizes, int n_in,
                              void* d_out, int out_size, void* d_ws, size_t ws_size,
                              hipStream_t stream) {
  const float* x  = (const float*)d_in[0];
  const float* Wg = (const float*)d_in[1];
  const float* W1 = (const float*)d_in[2];
  const float* W2 = (const float*)d_in[3];
  float* out = (float*)d_out;

  int*   counts = (int*)((char*)d_ws + WS_COUNTS);
  int*   tokl   = (int*)((char*)d_ws + WS_TOKL);
  float* wgtl   = (float*)((char*)d_ws + WS_WGTL);

  hipMemsetAsync(counts, 0, 256, stream);
  hipMemsetAsync(d_out, 0, (size_t)out_size * sizeof(float), stream);

  gate_kernel<<<NTOK / 4, 256, 0, stream>>>(x, Wg, counts, tokl, wgtl);

  if (ws_size >= WS_NEED) {
    unsigned short* xbf = (unsigned short*)((char*)d_ws + WS_XBF);
    unsigned short* W1s = (unsigned short*)((char*)d_ws + WS_W1S);
    unsigned short* W2s = (unsigned short*)((char*)d_ws + WS_W2S);
    convert_x<<<4096, 512, 0, stream>>>(x, xbf);
    convert_w<<<16384, 512, 0, stream>>>(W1, W2, W1s, W2s);
    hipFuncSetAttribute((const void*)ffn3,
                        hipFuncAttributeMaxDynamicSharedMemorySize, F3_TOTAL);
    ffn3<<<2048, 1024, F3_TOTAL, stream>>>(xbf, W1s, W2s, counts, tokl, wgtl, out);
  } else {
    hipFuncSetAttribute((const void*)ffn_kernel,
                        hipFuncAttributeMaxDynamicSharedMemorySize, SM_TOTAL);
    dim3 g(NTOK / 64, NEXP);
    ffn_kernel<<<g, 512, SM_TOTAL, stream>>>(x, W1, W2, counts, tokl, wgtl, out);
  }
}

// Round 4
// 766.645 us; speedup vs baseline: 2.2176x; 1.0897x over previous
//
#include <hip/hip_runtime.h>
#include <hip/hip_bf16.h>

#define NTOK 8192   // B*T tokens
#define DDIM 1024
#define FDIM 2048
#define NEXP 16
#define CAP   1280  // max token slots per expert (cnt ~1024 expected)
#define CAPRG 80    // CAP/16 row-groups

// ---------------- workspace layout (bytes) ----------------
// shared region (both paths)
#define WS_COUNTS 0
#define WS_TOKL   4096
#define WS_WGTL   (4096 + NTOK*NEXP*4)
// new path (unfused grouped GEMMs)
#define WS2_XG   (size_t)(2u<<20)     // 40 MB: 16*80*32 chunks x 1KB
#define WS2_W1   (size_t)(42u<<20)    // 64 MB frag-ordered bf16 W1
#define WS2_W2   (size_t)(106u<<20)   // 64 MB frag-ordered bf16 W2
#define WS2_UG   (size_t)(170u<<20)   // 80 MB: 16*80*64 chunks x 1KB
#define WS2_NEED (size_t)(250u<<20)
// fallback path (round-3 ffn3)
#define WS_XBF    (size_t)(2u<<20)
#define WS_W1S    (size_t)(32u<<20)
#define WS_W2S    (size_t)(96u<<20)
#define WS_NEED   (size_t)(160u<<20)

// ffn3 LDS layout
#define F3_XS 0
#define F3_UT 131072
#define F3_TK 147456
#define F3_WG 147712
#define F3_TOTAL 147968

typedef short bf16x8 __attribute__((ext_vector_type(8)));
typedef float f32x4  __attribute__((ext_vector_type(4)));

__device__ __forceinline__ unsigned short f2bf(float f) {
  unsigned int u = __builtin_bit_cast(unsigned int, f);
  u += 0x7fffu + ((u >> 16) & 1u);            // RNE
  return (unsigned short)(u >> 16);
}
__device__ __forceinline__ unsigned int pk2(float a, float b) {
  return (unsigned int)f2bf(a) | ((unsigned int)f2bf(b) << 16);
}
__device__ __forceinline__ float silu_f(float s) {
  return s / (1.f + __expf(-s));
}
__device__ __forceinline__ void gld_lds16(const void* g, void* l) {
  __builtin_amdgcn_global_load_lds((const __attribute__((address_space(1))) void*)g,
                                   (__attribute__((address_space(3))) void*)l, 16, 0, 0);
}

// ---------------- gate: logits -> top2 -> softmax -> per-expert lists ----------------
__global__ __launch_bounds__(256) void gate_kernel(
    const float* __restrict__ x, const float* __restrict__ Wg,
    int* __restrict__ counts, int* __restrict__ tokl, float* __restrict__ wgtl) {
  int gtid = blockIdx.x * blockDim.x + threadIdx.x;
  int tok = gtid >> 6;
  int lane = threadIdx.x & 63;
  if (tok >= NTOK) return;
  const float* xr = x + (size_t)tok * DDIM;
  float xv[16];
#pragma unroll
  for (int j = 0; j < 16; ++j) xv[j] = xr[lane + 64 * j];
  float lg[NEXP];
#pragma unroll
  for (int e = 0; e < NEXP; ++e) {
    float s = 0.f;
#pragma unroll
    for (int j = 0; j < 16; ++j) s += xv[j] * Wg[(lane + 64 * j) * NEXP + e];
#pragma unroll
    for (int off = 32; off > 0; off >>= 1) s += __shfl_xor(s, off);
    lg[e] = s;
  }
  int e0 = 0; float b0 = lg[0];
#pragma unroll
  for (int e = 1; e < NEXP; ++e) if (lg[e] > b0) { b0 = lg[e]; e0 = e; }
  int e1 = -1; float b1 = -3.4e38f;
#pragma unroll
  for (int e = 0; e < NEXP; ++e) if (e != e0 && lg[e] > b1) { b1 = lg[e]; e1 = e; }
  float t = expf(b1 - b0);
  float w0 = 1.f / (1.f + t);
  float w1 = t / (1.f + t);
  if (lane == 0) {
    int p = atomicAdd(&counts[e0], 1);
    tokl[e0 * NTOK + p] = tok; wgtl[e0 * NTOK + p] = w0;
    p = atomicAdd(&counts[e1], 1);
    tokl[e1 * NTOK + p] = tok; wgtl[e1 * NTOK + p] = w1;
  }
}

// ---------------- W fp32 -> bf16 frag-ordered, LDS-transposed (coalesced reads) ----
// W1s chunk (e*128+ff)*32+kk : elem (f=ff*16+llo, k=kk*32+lhi*8+j) at lane*8+j
// W2s chunk (e*64+kk)*64+cc  : elem (d=cc*16+llo, k=kk*32+lhi*8+j) at lane*8+j
__global__ __launch_bounds__(256) void convert_w2(
    const float* __restrict__ W1, const float* __restrict__ W2,
    unsigned short* __restrict__ W1s, unsigned short* __restrict__ W2s) {
  __shared__ float tile[32][133];
  int b = blockIdx.x;
  bool isw2 = b >= 8192;
  int bb = isw2 ? b - 8192 : b;
  int e = bb >> 9;
  int r = bb & 511;
  int t = threadIdx.x;
  const float* src;
  int kk, cb, C;
  if (!isw2) {
    kk = r >> 4; cb = r & 15; C = FDIM;
    src = W1 + ((size_t)e << 21) + (size_t)(kk * 32) * FDIM + cb * 128;
  } else {
    kk = r >> 3; cb = r & 7; C = DDIM;
    src = W2 + ((size_t)e << 21) + (size_t)(kk * 32) * DDIM + cb * 128;
  }
  int c4 = (t & 31) * 4, rr0 = t >> 5;
#pragma unroll
  for (int rd = 0; rd < 4; ++rd) {
    int rr = rr0 + rd * 8;
    float4 v = *(const float4*)(src + (size_t)rr * C + c4);
    tile[rr][c4] = v.x; tile[rr][c4 + 1] = v.y;
    tile[rr][c4 + 2] = v.z; tile[rr][c4 + 3] = v.w;
  }
  __syncthreads();
  int w = t >> 6, lane = t & 63, llo = lane & 15, lhi = lane >> 4;
#pragma unroll
  for (int u = 0; u < 2; ++u) {
    int c2 = w * 2 + u;
    float v[8];
#pragma unroll
    for (int j = 0; j < 8; ++j) v[j] = tile[lhi * 8 + j][c2 * 16 + llo];
    uint4 o;
    o.x = pk2(v[0], v[1]); o.y = pk2(v[2], v[3]);
    o.z = pk2(v[4], v[5]); o.w = pk2(v[6], v[7]);
    size_t gid = isw2 ? (((size_t)e * 64 + kk) * 64 + (cb * 8 + c2))
                      : (((size_t)e * 128 + (cb * 8 + c2)) * 32 + kk);
    *(uint4*)((isw2 ? W2s : W1s) + (gid << 9) + lane * 8) = o;
  }
}

// ---------------- gather x -> Xg frag-ordered bf16, zero-padded slots ----------------
// Xg chunk (e*CAPRG+rg)*32+kb : elem (slot=rg*16+llo, k=kb*32+lhi*8+j) at lane*8+j
__global__ __launch_bounds__(512) void gather_x(
    const float* __restrict__ x, const int* __restrict__ counts,
    const int* __restrict__ tokl, unsigned short* __restrict__ Xg) {
  int chunk = blockIdx.x * 8 + (threadIdx.x >> 6);   // 40960 chunks
  int lane = threadIdx.x & 63, llo = lane & 15, lhi = lane >> 4;
  int kb = chunk & 31;
  int rg = (chunk >> 5) % CAPRG;
  int e = chunk / (CAPRG * 32);
  int cnt = min(counts[e], CAP);
  int slot = rg * 16 + llo;
  uint4 o = {0u, 0u, 0u, 0u};
  if (slot < cnt) {
    int tok = tokl[e * NTOK + slot];
    const float* p = x + (size_t)tok * DDIM + kb * 32 + lhi * 8;
    float4 a = *(const float4*)p, b2 = *(const float4*)(p + 4);
    o.x = pk2(a.x, a.y); o.y = pk2(a.z, a.w);
    o.z = pk2(b2.x, b2.y); o.w = pk2(b2.z, b2.w);
  }
  *(uint4*)(Xg + ((size_t)chunk << 9) + lane * 8) = o;
}

// ---------------- G1: U = silu(X @ W1e), 128f x 256tok blocks, no barriers ----------
__global__ __launch_bounds__(512, 4) void g1(
    const unsigned short* __restrict__ W1s, const unsigned short* __restrict__ Xg,
    const int* __restrict__ counts, unsigned short* __restrict__ Ug) {
  int id = blockIdx.x;
  int e = ((id & 7) << 1) | ((id >> 3) & 1);  // expert pair per XCD
  int rest = id >> 4;
  int ft = rest & 15;          // f-tile (128 f)
  int tt = rest >> 4;          // tok-tile (256 slots), 0..4
  int cnt = min(counts[e], CAP);
  int tb0 = tt * 256;
  if (tb0 >= cnt) return;
  int tid = threadIdx.x, wid = tid >> 6, lane = tid & 63;
  int llo = lane & 15, lhi = lane >> 4;
  int wf = wid >> 2, wt = wid & 3;             // 2 f-groups x 4 tok-groups
  int fb = ft * 128 + wf * 64;
  int tb = tb0 + wt * 64;

  const unsigned short* ap =
      W1s + ((((size_t)e * 128 + (fb >> 4)) * 32) << 9) + lane * 8;
  const unsigned short* bp =
      Xg + ((((size_t)e * CAPRG + (tb >> 4)) * 32) << 9) + lane * 8;

  f32x4 acc[4][4];
#pragma unroll
  for (int i = 0; i < 4; ++i)
#pragma unroll
    for (int j = 0; j < 4; ++j) acc[i][j] = (f32x4){0.f, 0.f, 0.f, 0.f};

  bf16x8 a_c[4], b_c[4];
#pragma unroll
  for (int i = 0; i < 4; ++i) {
    a_c[i] = *(const bf16x8*)(ap + (size_t)i * 16384);
    b_c[i] = *(const bf16x8*)(bp + (size_t)i * 16384);
  }
  for (int kk = 0; kk < 32; ++kk) {
    bf16x8 a_n[4];
    if (kk < 31) {
#pragma unroll
      for (int i = 0; i < 4; ++i)
        a_n[i] = *(const bf16x8*)(ap + (size_t)(i * 32 + kk + 1) * 512);
    }
#pragma unroll
    for (int ti = 0; ti < 4; ++ti) {
      bf16x8 bcur = b_c[ti];
      if (kk < 31)
        b_c[ti] = *(const bf16x8*)(bp + (size_t)(ti * 32 + kk + 1) * 512);
      acc[0][ti] = __builtin_amdgcn_mfma_f32_16x16x32_bf16(a_c[0], bcur, acc[0][ti], 0, 0, 0);
      acc[1][ti] = __builtin_amdgcn_mfma_f32_16x16x32_bf16(a_c[1], bcur, acc[1][ti], 0, 0, 0);
      acc[2][ti] = __builtin_amdgcn_mfma_f32_16x16x32_bf16(a_c[2], bcur, acc[2][ti], 0, 0, 0);
      acc[3][ti] = __builtin_amdgcn_mfma_f32_16x16x32_bf16(a_c[3], bcur, acc[3][ti], 0, 0, 0);
    }
    if (kk < 31) {
#pragma unroll
      for (int i = 0; i < 4; ++i) a_c[i] = a_n[i];
    }
  }

  // epilogue: silu -> per-wave LDS transpose -> frag-ordered Ug
  extern __shared__ char smem[];
  char* wl = smem + wid * 9216;   // [64 tok][64 f] bf16, row stride 144 B
#pragma unroll
  for (int fi = 0; fi < 4; ++fi)
#pragma unroll
    for (int ti = 0; ti < 4; ++ti) {
      uint2 pv;
      pv.x = pk2(silu_f(acc[fi][ti][0]), silu_f(acc[fi][ti][1]));
      pv.y = pk2(silu_f(acc[fi][ti][2]), silu_f(acc[fi][ti][3]));
      *(uint2*)(wl + (ti * 16 + llo) * 144 + (fi * 16 + 4 * lhi) * 2) = pv;
    }
#pragma unroll
  for (int c = 0; c < 8; ++c) {
    int ti2 = c >> 1, kb = c & 1;
    uint4 v = *(const uint4*)(wl + (ti2 * 16 + llo) * 144 + (kb * 32 + lhi * 8) * 2);
    size_t ug = (((size_t)e * CAPRG + (tb >> 4) + ti2) * 64 + (fb >> 5) + kb) * 512
                + lane * 8;
    *(uint4*)(Ug + ug) = v;
  }
}

// ---------------- G2: Y += w * (U @ W2e), 128d x 256tok blocks ----------------
__global__ __launch_bounds__(512, 4) void g2(
    const unsigned short* __restrict__ W2s, const unsigned short* __restrict__ Ug,
    const int* __restrict__ counts, const int* __restrict__ tokl,
    const float* __restrict__ wgtl, float* __restrict__ out) {
  int id = blockIdx.x;
  int e = ((id & 7) << 1) | ((id >> 3) & 1);
  int rest = id >> 4;
  int dt = rest & 7;           // d-tile (128 d)
  int tt = rest >> 3;          // 0..4
  int cnt = min(counts[e], CAP);
  int tb0 = tt * 256;
  if (tb0 >= cnt) return;
  __shared__ int tks[256];
  __shared__ float wgs[256];
  int tid = threadIdx.x;
  if (tid < 256) {
    int s = tb0 + tid;
    tks[tid] = (s < cnt) ? tokl[e * NTOK + s] : -1;
    wgs[tid] = (s < cnt) ? wgtl[e * NTOK + s] : 0.f;
  }
  __syncthreads();
  int wid = tid >> 6, lane = tid & 63, llo = lane & 15, lhi = lane >> 4;
  int wd = wid >> 2, wt = wid & 3;
  int db = dt * 128 + wd * 64;
  int tb = tb0 + wt * 64;

  const unsigned short* ap =
      W2s + (((size_t)e * 4096 + (db >> 4)) << 9) + lane * 8;
  const unsigned short* bp =
      Ug + ((((size_t)e * CAPRG + (tb >> 4)) * 64) << 9) + lane * 8;

  f32x4 acc[4][4];
#pragma unroll
  for (int i = 0; i < 4; ++i)
#pragma unroll
    for (int j = 0; j < 4; ++j) acc[i][j] = (f32x4){0.f, 0.f, 0.f, 0.f};

  bf16x8 a_c[4], b_c[4];
#pragma unroll
  for (int i = 0; i < 4; ++i) {
    a_c[i] = *(const bf16x8*)(ap + (size_t)i * 512);
    b_c[i] = *(const bf16x8*)(bp + (size_t)(i * 64) * 512);
  }
  for (int kk = 0; kk < 64; ++kk) {
    bf16x8 a_n[4];
    if (kk < 63) {
#pragma unroll
      for (int i = 0; i < 4; ++i)
        a_n[i] = *(const bf16x8*)(ap + (size_t)((kk + 1) * 64 + i) * 512);
    }
#pragma unroll
    for (int ti = 0; ti < 4; ++ti) {
      bf16x8 bcur = b_c[ti];
      if (kk < 63)
        b_c[ti] = *(const bf16x8*)(bp + (size_t)(ti * 64 + kk + 1) * 512);
      acc[0][ti] = __builtin_amdgcn_mfma_f32_16x16x32_bf16(a_c[0], bcur, acc[0][ti], 0, 0, 0);
      acc[1][ti] = __builtin_amdgcn_mfma_f32_16x16x32_bf16(a_c[1], bcur, acc[1][ti], 0, 0, 0);
      acc[2][ti] = __builtin_amdgcn_mfma_f32_16x16x32_bf16(a_c[2], bcur, acc[2][ti], 0, 0, 0);
      acc[3][ti] = __builtin_amdgcn_mfma_f32_16x16x32_bf16(a_c[3], bcur, acc[3][ti], 0, 0, 0);
    }
    if (kk < 63) {
#pragma unroll
      for (int i = 0; i < 4; ++i) a_c[i] = a_n[i];
    }
  }

  int tloc = wt * 64;
#pragma unroll
  for (int di = 0; di < 4; ++di)
#pragma unroll
    for (int ti = 0; ti < 4; ++ti) {
      int sidx = tloc + ti * 16 + llo;
      int tok = tks[sidx];
      if (tok >= 0) {
        float w = wgs[sidx];
        size_t orow = (size_t)tok * DDIM + db + di * 16 + 4 * lhi;
#pragma unroll
        for (int reg = 0; reg < 4; ++reg)
          atomicAdd(out + orow + reg, acc[di][ti][reg] * w);
      }
    }
}

// ================= fallback path (round-3, ws < 250 MB) =================
__global__ __launch_bounds__(512) void convert_x(const float* __restrict__ x,
                                                 unsigned short* __restrict__ xbf) {
  int i = blockIdx.x * 512 + threadIdx.x;
  float4 v = ((const float4*)x)[i];
  uint2 o; o.x = pk2(v.x, v.y); o.y = pk2(v.z, v.w);
  ((uint2*)xbf)[i] = o;
}

__global__ __launch_bounds__(512) void convert_w(
    const float* __restrict__ W1, const float* __restrict__ W2,
    unsigned short* __restrict__ W1s, unsigned short* __restrict__ W2s) {
  int gid = blockIdx.x * 8 + (threadIdx.x >> 6);
  int lane = threadIdx.x & 63, llo = lane & 15, lhi = lane >> 4;
  const float* src;
  unsigned short* dst;
  int C;
  if (gid < 65536) {
    int e = gid >> 12, ff = (gid >> 5) & 127, kk = gid & 31;
    src = W1 + ((size_t)e << 21) + (size_t)(kk * 32 + lhi * 8) * FDIM + ff * 16 + llo;
    dst = W1s + ((size_t)gid << 9) + lane * 8;
    C = FDIM;
  } else {
    int g = gid - 65536;
    int e = g >> 12, kk = (g >> 6) & 63, cc = g & 63;
    src = W2 + ((size_t)e << 21) + (size_t)(kk * 32 + lhi * 8) * DDIM + cc * 16 + llo;
    dst = W2s + ((size_t)g << 9) + lane * 8;
    C = DDIM;
  }
  float v[8];
#pragma unroll
  for (int j = 0; j < 8; ++j) v[j] = src[(size_t)j * C];
  uint4 o;
  o.x = pk2(v[0], v[1]); o.y = pk2(v[2], v[3]);
  o.z = pk2(v[4], v[5]); o.w = pk2(v[6], v[7]);
  *(uint4*)dst = o;
}

__global__ __launch_bounds__(1024, 4) void ffn3(
    const unsigned short* __restrict__ xbf,
    const unsigned short* __restrict__ W1s,
    const unsigned short* __restrict__ W2s,
    const int* __restrict__ counts, const int* __restrict__ tokl,
    const float* __restrict__ wgtl, float* __restrict__ out) {
  int id = blockIdx.x;
  int e = ((id & 7) << 1) | ((id >> 3) & 1);
  int tile = id >> 4;
  int cnt = counts[e];
  int base = tile * 64;
  if (base >= cnt) return;
  int m = min(64, cnt - base);

  extern __shared__ char smem[];
  char* xs = smem + F3_XS;
  char* uts = smem + F3_UT;
  int* tks = (int*)(smem + F3_TK);
  float* wgs = (float*)(smem + F3_WG);

  int tid = threadIdx.x, wid = tid >> 6, lane = tid & 63;
  int llo = lane & 15, lhi = lane >> 4;

  if (tid < 64) {
    int tk = 0; float w = 0.f;
    if (tid < m) { tk = tokl[e * NTOK + base + tid]; w = wgtl[e * NTOK + base + tid]; }
    tks[tid] = tk; wgs[tid] = w;
  }
  __syncthreads();

#pragma unroll
  for (int i = 0; i < 8; ++i) {
    int chunk = wid * 8 + i;
    int r = chunk >> 1;
    int pos = ((chunk & 1) << 6) | lane;
    const unsigned short* src =
        xbf + ((size_t)tks[r] << 10) + ((pos ^ (r & 7)) << 3);
    gld_lds16(src, xs + (chunk << 10));
  }
  __syncthreads();

  const unsigned short* w1e = W1s + ((size_t)e << 21);
  const unsigned short* w2e = W2s + ((size_t)e << 21);
  const int fw = wid >> 1;
  const int rwb = (wid & 1) * 32;
  const int cwb = wid * 64;

  f32x4 acc[4][4];
#pragma unroll
  for (int i = 0; i < 4; ++i)
#pragma unroll
    for (int j = 0; j < 4; ++j) acc[i][j] = (f32x4){0.f, 0.f, 0.f, 0.f};

  const int r0 = rwb + llo, r1 = r0 + 16;
  const int sw0 = r0 & 7;

  bf16x8 afc[4];
  {
    const unsigned short* w1p = w1e + ((size_t)fw << 14);
#pragma unroll
    for (int j = 0; j < 4; ++j)
      afc[j] = *(const bf16x8*)(w1p + (j << 9) + lane * 8);
  }

  for (int fci = 0; fci < 16; ++fci) {
    const unsigned short* w1p = w1e + ((size_t)(fci * 8 + fw) << 14);
    f32x4 acc1[2];
    acc1[0] = (f32x4){0.f, 0.f, 0.f, 0.f};
    acc1[1] = (f32x4){0.f, 0.f, 0.f, 0.f};
#pragma unroll
    for (int kk4 = 0; kk4 < 8; ++kk4) {
      bf16x8 afn[4];
      if (kk4 < 7) {
#pragma unroll
        for (int j = 0; j < 4; ++j)
          afn[j] = *(const bf16x8*)(w1p + ((kk4 * 4 + 4 + j) << 9) + lane * 8);
      }
#pragma unroll
      for (int j = 0; j < 4; ++j) {
        int jo = ((kk4 * 4 + j) << 2) + lhi;
        bf16x8 bx0 = *(const bf16x8*)(xs + (r0 << 11) + ((jo ^ sw0) << 4));
        bf16x8 bx1 = *(const bf16x8*)(xs + (r1 << 11) + ((jo ^ sw0) << 4));
        acc1[0] = __builtin_amdgcn_mfma_f32_16x16x32_bf16(afc[j], bx0, acc1[0], 0, 0, 0);
        acc1[1] = __builtin_amdgcn_mfma_f32_16x16x32_bf16(afc[j], bx1, acc1[1], 0, 0, 0);
      }
      if (kk4 < 7) {
#pragma unroll
        for (int j = 0; j < 4; ++j) afc[j] = afn[j];
      }
    }
#pragma unroll
    for (int ri = 0; ri < 2; ++ri) {
      int r = rwb + ri * 16 + llo;
      int fbx = fw * 16 + lhi * 4;
      uint2 pv;
      pv.x = pk2(silu_f(acc1[ri][0]), silu_f(acc1[ri][1]));
      pv.y = pk2(silu_f(acc1[ri][2]), silu_f(acc1[ri][3]));
      *(uint2*)(uts + (r << 8) + (((fbx >> 3) ^ (r & 7)) << 4) + ((fbx & 7) << 1)) = pv;
    }
    bf16x8 bwc[4];
    {
      const unsigned short* w2p = w2e + ((size_t)((fci * 4) * 64 + wid * 4) << 9);
#pragma unroll
      for (int ci = 0; ci < 4; ++ci)
        bwc[ci] = *(const bf16x8*)(w2p + (ci << 9) + lane * 8);
    }
    asm volatile("s_waitcnt lgkmcnt(0)" ::: "memory");
    __builtin_amdgcn_s_barrier();

#pragma unroll
    for (int ks = 0; ks < 4; ++ks) {
      bf16x8 bwn[4];
      if (ks < 3) {
        const unsigned short* w2q =
            w2e + ((size_t)((fci * 4 + ks + 1) * 64 + wid * 4) << 9);
#pragma unroll
        for (int ci = 0; ci < 4; ++ci)
          bwn[ci] = *(const bf16x8*)(w2q + (ci << 9) + lane * 8);
      }
      bf16x8 au[4];
#pragma unroll
      for (int ri = 0; ri < 4; ++ri) {
        int r = ri * 16 + llo;
        int po = (ks << 2) + lhi;
        au[ri] = *(const bf16x8*)(uts + (r << 8) + ((po ^ (r & 7)) << 4));
      }
#pragma unroll
      for (int ri = 0; ri < 4; ++ri)
#pragma unroll
        for (int ci = 0; ci < 4; ++ci)
          acc[ri][ci] = __builtin_amdgcn_mfma_f32_16x16x32_bf16(au[ri], bwc[ci], acc[ri][ci], 0, 0, 0);
      if (ks < 3) {
#pragma unroll
        for (int ci = 0; ci < 4; ++ci) bwc[ci] = bwn[ci];
      }
    }
    if (fci < 15) {
      const unsigned short* w1n = w1e + ((size_t)((fci + 1) * 8 + fw) << 14);
#pragma unroll
      for (int j = 0; j < 4; ++j)
        afc[j] = *(const bf16x8*)(w1n + (j << 9) + lane * 8);
    }
    asm volatile("s_waitcnt lgkmcnt(0)" ::: "memory");
    __builtin_amdgcn_s_barrier();
  }

#pragma unroll
  for (int ri = 0; ri < 4; ++ri)
#pragma unroll
    for (int reg = 0; reg < 4; ++reg) {
      int r = ri * 16 + 4 * lhi + reg;
      if (r < m) {
        float w = wgs[r];
        size_t orow = (size_t)tks[r] * DDIM;
#pragma unroll
        for (int ci = 0; ci < 4; ++ci)
          atomicAdd(&out[orow + cwb + ci * 16 + llo], acc[ri][ci][reg] * w);
      }
    }
}

extern "C" void kernel_launch(void* const* d_in, const int* in_sizes, int n_in,
                              void* d_out, int out_size, void* d_ws, size_t ws_size,
                              hipStream_t stream) {
  const float* x  = (const float*)d_in[0];
  const float* Wg = (const float*)d_in[1];
  const float* W1 = (const float*)d_in[2];
  const float* W2 = (const float*)d_in[3];
  float* out = (float*)d_out;

  int*   counts = (int*)((char*)d_ws + WS_COUNTS);
  int*   tokl   = (int*)((char*)d_ws + WS_TOKL);
  float* wgtl   = (float*)((char*)d_ws + WS_WGTL);

  hipMemsetAsync(counts, 0, 256, stream);
  hipMemsetAsync(d_out, 0, (size_t)out_size * sizeof(float), stream);

  gate_kernel<<<NTOK / 4, 256, 0, stream>>>(x, Wg, counts, tokl, wgtl);

  if (ws_size >= WS2_NEED) {
    unsigned short* XgN = (unsigned short*)((char*)d_ws + WS2_XG);
    unsigned short* W1n = (unsigned short*)((char*)d_ws + WS2_W1);
    unsigned short* W2n = (unsigned short*)((char*)d_ws + WS2_W2);
    unsigned short* UgN = (unsigned short*)((char*)d_ws + WS2_UG);
    convert_w2<<<16384, 256, 0, stream>>>(W1, W2, W1n, W2n);
    gather_x<<<5120, 512, 0, stream>>>(x, counts, tokl, XgN);
    hipFuncSetAttribute((const void*)g1,
                        hipFuncAttributeMaxDynamicSharedMemorySize, 73728);
    g1<<<NEXP * 16 * 5, 512, 73728, stream>>>(W1n, XgN, counts, UgN);
    g2<<<NEXP * 8 * 5, 512, 0, stream>>>(W2n, UgN, counts, tokl, wgtl, out);
  } else {
    unsigned short* xbf = (unsigned short*)((char*)d_ws + WS_XBF);
    unsigned short* W1s = (unsigned short*)((char*)d_ws + WS_W1S);
    unsigned short* W2s = (unsigned short*)((char*)d_ws + WS_W2S);
    convert_x<<<4096, 512, 0, stream>>>(x, xbf);
    convert_w<<<16384, 512, 0, stream>>>(W1, W2, W1s, W2s);
    hipFuncSetAttribute((const void*)ffn3,
                        hipFuncAttributeMaxDynamicSharedMemorySize, F3_TOTAL);
    ffn3<<<2048, 1024, F3_TOTAL, stream>>>(xbf, W1s, W2s, counts, tokl, wgtl, out);
  }
}

// Round 5
// 688.373 us; speedup vs baseline: 2.4697x; 1.1137x over previous
//
#include <hip/hip_runtime.h>
#include <hip/hip_bf16.h>

#define NTOK 8192   // B*T tokens
#define DDIM 1024
#define FDIM 2048
#define NEXP 16
#define CAP   1280  // max token slots per expert (cnt ~1024 expected)
#define CAPRG 80    // CAP/16 row-groups

// ---------------- workspace layout (bytes) ----------------
#define WS_COUNTS 0
#define WS_TOKL   4096
#define WS_WGTL   (4096 + NTOK*NEXP*4)
#define WS2_XG   (size_t)(2u<<20)     // 40 MB: 16*80*32 chunks x 1KB  (std frag order)
#define WS2_W1   (size_t)(42u<<20)    // 64 MB: 16*128*32 chunks       (std frag order)
#define WS2_W2   (size_t)(106u<<20)   // 64 MB: 16*64*64 chunks        (SIGMA frag order)
#define WS2_UG   (size_t)(170u<<20)   // 80 MB: 16*80*64 chunks        (SIGMA frag order)

typedef short bf16x8 __attribute__((ext_vector_type(8)));
typedef float f32x4  __attribute__((ext_vector_type(4)));

__device__ __forceinline__ unsigned short f2bf(float f) {
  unsigned int u = __builtin_bit_cast(unsigned int, f);
  u += 0x7fffu + ((u >> 16) & 1u);            // RNE
  return (unsigned short)(u >> 16);
}
__device__ __forceinline__ unsigned int pk2(float a, float b) {
  return (unsigned int)f2bf(a) | ((unsigned int)f2bf(b) << 16);
}
__device__ __forceinline__ float silu_f(float s) {
  return s / (1.f + __expf(-s));
}
__device__ __forceinline__ void gld_lds16(const void* g, void* l) {
  __builtin_amdgcn_global_load_lds((const __attribute__((address_space(1))) void*)g,
                                   (__attribute__((address_space(3))) void*)l, 16, 0, 0);
}

// ---------------- gate: logits -> top2 -> softmax -> per-expert lists ----------------
__global__ __launch_bounds__(256) void gate_kernel(
    const float* __restrict__ x, const float* __restrict__ Wg,
    int* __restrict__ counts, int* __restrict__ tokl, float* __restrict__ wgtl) {
  int gtid = blockIdx.x * blockDim.x + threadIdx.x;
  int tok = gtid >> 6;
  int lane = threadIdx.x & 63;
  if (tok >= NTOK) return;
  const float* xr = x + (size_t)tok * DDIM;
  float xv[16];
#pragma unroll
  for (int j = 0; j < 16; ++j) xv[j] = xr[lane + 64 * j];
  float lg[NEXP];
#pragma unroll
  for (int e = 0; e < NEXP; ++e) {
    float s = 0.f;
#pragma unroll
    for (int j = 0; j < 16; ++j) s += xv[j] * Wg[(lane + 64 * j) * NEXP + e];
#pragma unroll
    for (int off = 32; off > 0; off >>= 1) s += __shfl_xor(s, off);
    lg[e] = s;
  }
  int e0 = 0; float b0 = lg[0];
#pragma unroll
  for (int e = 1; e < NEXP; ++e) if (lg[e] > b0) { b0 = lg[e]; e0 = e; }
  int e1 = -1; float b1 = -3.4e38f;
#pragma unroll
  for (int e = 0; e < NEXP; ++e) if (e != e0 && lg[e] > b1) { b1 = lg[e]; e1 = e; }
  float t = expf(b1 - b0);
  float w0 = 1.f / (1.f + t);
  float w1 = t / (1.f + t);
  if (lane == 0) {
    int p = atomicAdd(&counts[e0], 1);
    tokl[e0 * NTOK + p] = tok; wgtl[e0 * NTOK + p] = w0;
    p = atomicAdd(&counts[e1], 1);
    tokl[e1 * NTOK + p] = tok; wgtl[e1 * NTOK + p] = w1;
  }
}

// ---------------- W fp32 -> bf16 frag-ordered, LDS-transposed (coalesced reads) ----
// W1s chunk (e*128+ff)*32+kk : elem(lane,j) = W1[e][kk*32+lhi*8+j][ff*16+llo]
// W2s chunk (e*64+kk)*64+cc  : elem(lane,j) = W2[e][kk*32+SIGMA(lhi,j)][cc*16+llo]
//   SIGMA(lhi,j) = 4*lhi + (j&3) + 16*(j>>2)   (must match Ug packing in g1)
__global__ __launch_bounds__(256) void convert_w2(
    const float* __restrict__ W1, const float* __restrict__ W2,
    unsigned short* __restrict__ W1s, unsigned short* __restrict__ W2s) {
  __shared__ float tile[32][133];
  int b = blockIdx.x;
  bool isw2 = b >= 8192;
  int bb = isw2 ? b - 8192 : b;
  int e = bb >> 9;
  int r = bb & 511;
  int t = threadIdx.x;
  const float* src;
  int kk, cb, C;
  if (!isw2) {
    kk = r >> 4; cb = r & 15; C = FDIM;
    src = W1 + ((size_t)e << 21) + (size_t)(kk * 32) * FDIM + cb * 128;
  } else {
    kk = r >> 3; cb = r & 7; C = DDIM;
    src = W2 + ((size_t)e << 21) + (size_t)(kk * 32) * DDIM + cb * 128;
  }
  int c4 = (t & 31) * 4, rr0 = t >> 5;
#pragma unroll
  for (int rd = 0; rd < 4; ++rd) {
    int rr = rr0 + rd * 8;
    float4 v = *(const float4*)(src + (size_t)rr * C + c4);
    tile[rr][c4] = v.x; tile[rr][c4 + 1] = v.y;
    tile[rr][c4 + 2] = v.z; tile[rr][c4 + 3] = v.w;
  }
  __syncthreads();
  int w = t >> 6, lane = t & 63, llo = lane & 15, lhi = lane >> 4;
#pragma unroll
  for (int u = 0; u < 2; ++u) {
    int c2 = w * 2 + u;
    float v[8];
#pragma unroll
    for (int j = 0; j < 8; ++j) {
      int row = isw2 ? (4 * lhi + (j & 3) + 16 * (j >> 2)) : (lhi * 8 + j);
      v[j] = tile[row][c2 * 16 + llo];
    }
    uint4 o;
    o.x = pk2(v[0], v[1]); o.y = pk2(v[2], v[3]);
    o.z = pk2(v[4], v[5]); o.w = pk2(v[6], v[7]);
    size_t gid = isw2 ? (((size_t)e * 64 + kk) * 64 + (cb * 8 + c2))
                      : (((size_t)e * 128 + (cb * 8 + c2)) * 32 + kk);
    *(uint4*)((isw2 ? W2s : W1s) + (gid << 9) + lane * 8) = o;
  }
}

// ---------------- gather x -> Xg frag-ordered bf16, zero-padded slots ----------------
// Xg chunk (e*CAPRG+rg)*32+kb : elem(lane,j) = x[tok(rg*16+llo)][kb*32+lhi*8+j]
__global__ __launch_bounds__(512) void gather_x(
    const float* __restrict__ x, const int* __restrict__ counts,
    const int* __restrict__ tokl, unsigned short* __restrict__ Xg) {
  int chunk = blockIdx.x * 8 + (threadIdx.x >> 6);   // 40960 chunks
  int lane = threadIdx.x & 63, llo = lane & 15, lhi = lane >> 4;
  int kb = chunk & 31;
  int rg = (chunk >> 5) % CAPRG;
  int e = chunk / (CAPRG * 32);
  int cnt = min(counts[e], CAP);
  int slot = rg * 16 + llo;
  uint4 o = {0u, 0u, 0u, 0u};
  if (slot < cnt) {
    int tok = tokl[e * NTOK + slot];
    const float* p = x + (size_t)tok * DDIM + kb * 32 + lhi * 8;
    float4 a = *(const float4*)p, b2 = *(const float4*)(p + 4);
    o.x = pk2(a.x, a.y); o.y = pk2(a.z, a.w);
    o.z = pk2(b2.x, b2.y); o.w = pk2(b2.z, b2.w);
  }
  *(uint4*)(Xg + ((size_t)chunk << 9) + lane * 8) = o;
}

// ---------------- G1: U = silu(X @ W1e), m97-structure pipelined, 128f x 128tok ----
// 4 waves (2f x 2tok of 64x64), BK=64, single-buffer LDS 32KB, gload_lds w16.
// Epilogue: direct reg->Ug store in SIGMA order (no LDS, no transpose).
__global__ __launch_bounds__(256, 4) void g1(
    const unsigned short* __restrict__ W1s, const unsigned short* __restrict__ Xg,
    const int* __restrict__ counts, unsigned short* __restrict__ Ug) {
  int id = blockIdx.x;
  int e = ((id & 7) << 1) | ((id >> 3) & 1);  // 2 experts per XCD
  int rest = id >> 4;
  int ft = rest & 15;          // f-tile (128 f)
  int tt = rest >> 4;          // tok-tile (128 slots), 0..9
  int cnt = min(counts[e], CAP);
  if (tt * 128 >= cnt) return;

  __shared__ char smem[32768];                 // A: [0,16K) 16 chunks; B: [16K,32K)
  int tid = threadIdx.x, wid = tid >> 6, lane = tid & 63;
  int llo = lane & 15, lhi = lane >> 4;
  int wf = wid >> 1, wt2 = wid & 1;            // wave = f-half x tok-half

  f32x4 acc[4][4];
#pragma unroll
  for (int i = 0; i < 4; ++i)
#pragma unroll
    for (int j = 0; j < 4; ++j) acc[i][j] = (f32x4){0.f, 0.f, 0.f, 0.f};

  const size_t abase = ((size_t)e * 128 + ft * 8) * 32;      // W1s chunk base
  const size_t bbase = ((size_t)e * CAPRG + tt * 8) * 32;    // Xg  chunk base

  for (int t = 0; t < 16; ++t) {               // K = 1024, BK = 64
    // stage: 32 chunks of 1KB, 8 per wave
#pragma unroll
    for (int i = 0; i < 8; ++i) {
      int c = wid * 8 + i;
      if (c < 16) {
        int ff = c >> 1, kk = c & 1;
        gld_lds16(W1s + ((abase + (size_t)ff * 32 + t * 2 + kk) << 9) + lane * 8,
                  smem + c * 1024);
      } else {
        int cb = c - 16, rgl = cb >> 1, kk = cb & 1;
        gld_lds16(Xg + ((bbase + (size_t)rgl * 32 + t * 2 + kk) << 9) + lane * 8,
                  smem + 16384 + cb * 1024);
      }
    }
    __syncthreads();
#pragma unroll
    for (int kk = 0; kk < 2; ++kk) {
      bf16x8 af[4], bx[4];
#pragma unroll
      for (int fi = 0; fi < 4; ++fi)
        af[fi] = *(const bf16x8*)(smem + (((wf * 4 + fi) * 2 + kk) << 10) + lane * 16);
#pragma unroll
      for (int ti = 0; ti < 4; ++ti)
        bx[ti] = *(const bf16x8*)(smem + 16384 + (((wt2 * 4 + ti) * 2 + kk) << 10) + lane * 16);
#pragma unroll
      for (int fi = 0; fi < 4; ++fi)
#pragma unroll
        for (int ti = 0; ti < 4; ++ti)
          acc[fi][ti] = __builtin_amdgcn_mfma_f32_16x16x32_bf16(af[fi], bx[ti], acc[fi][ti], 0, 0, 0);
    }
    __syncthreads();
  }

  // epilogue: silu -> Ug (SIGMA order), coalesced 16B stores straight from regs
#pragma unroll
  for (int ti = 0; ti < 4; ++ti) {
    int rg = tt * 8 + wt2 * 4 + ti;
#pragma unroll
    for (int p = 0; p < 2; ++p) {
      int fo = ft * 4 + wf * 2 + p;
      uint4 v;
      v.x = pk2(silu_f(acc[2 * p][ti][0]), silu_f(acc[2 * p][ti][1]));
      v.y = pk2(silu_f(acc[2 * p][ti][2]), silu_f(acc[2 * p][ti][3]));
      v.z = pk2(silu_f(acc[2 * p + 1][ti][0]), silu_f(acc[2 * p + 1][ti][1]));
      v.w = pk2(silu_f(acc[2 * p + 1][ti][2]), silu_f(acc[2 * p + 1][ti][3]));
      *(uint4*)(Ug + ((((size_t)e * CAPRG + rg) * 64 + fo) << 9) + lane * 8) = v;
    }
  }
}

// ---------------- G2: Y += w * (U @ W2e), m97-structure pipelined, 128d x 128tok ----
__global__ __launch_bounds__(256, 4) void g2(
    const unsigned short* __restrict__ W2s, const unsigned short* __restrict__ Ug,
    const int* __restrict__ counts, const int* __restrict__ tokl,
    const float* __restrict__ wgtl, float* __restrict__ out) {
  int id = blockIdx.x;
  int e = ((id & 7) << 1) | ((id >> 3) & 1);
  int rest = id >> 4;
  int dt = rest & 7;           // d-tile (128 d)
  int tt = rest >> 3;          // tok-tile (128 slots), 0..9
  int cnt = min(counts[e], CAP);
  int tb0 = tt * 128;
  if (tb0 >= cnt) return;

  __shared__ char smem[32768];
  __shared__ int tks[128];
  __shared__ float wgs[128];
  int tid = threadIdx.x;
  if (tid < 128) {
    int s = tb0 + tid;
    tks[tid] = (s < cnt) ? tokl[e * NTOK + s] : -1;
    wgs[tid] = (s < cnt) ? wgtl[e * NTOK + s] : 0.f;
  }
  int wid = tid >> 6, lane = tid & 63, llo = lane & 15, lhi = lane >> 4;
  int wd = wid >> 1, wt2 = wid & 1;            // wave = d-half x tok-half

  f32x4 acc[4][4];
#pragma unroll
  for (int i = 0; i < 4; ++i)
#pragma unroll
    for (int j = 0; j < 4; ++j) acc[i][j] = (f32x4){0.f, 0.f, 0.f, 0.f};

  const size_t bbase = ((size_t)e * CAPRG + tt * 8) * 64;    // Ug chunk base

  for (int t = 0; t < 32; ++t) {               // K = 2048, BK = 64
#pragma unroll
    for (int i = 0; i < 8; ++i) {
      int c = wid * 8 + i;
      if (c < 16) {
        int cc = c >> 1, kk = c & 1;
        gld_lds16(W2s + ((((size_t)e * 64 + t * 2 + kk) * 64 + dt * 8 + cc) << 9) + lane * 8,
                  smem + c * 1024);
      } else {
        int cb = c - 16, rgl = cb >> 1, kk = cb & 1;
        gld_lds16(Ug + ((bbase + (size_t)rgl * 64 + t * 2 + kk) << 9) + lane * 8,
                  smem + 16384 + cb * 1024);
      }
    }
    __syncthreads();
#pragma unroll
    for (int kk = 0; kk < 2; ++kk) {
      bf16x8 aw[4], bu[4];
#pragma unroll
      for (int di = 0; di < 4; ++di)
        aw[di] = *(const bf16x8*)(smem + (((wd * 4 + di) * 2 + kk) << 10) + lane * 16);
#pragma unroll
      for (int ti = 0; ti < 4; ++ti)
        bu[ti] = *(const bf16x8*)(smem + 16384 + (((wt2 * 4 + ti) * 2 + kk) << 10) + lane * 16);
#pragma unroll
      for (int di = 0; di < 4; ++di)
#pragma unroll
        for (int ti = 0; ti < 4; ++ti)
          acc[di][ti] = __builtin_amdgcn_mfma_f32_16x16x32_bf16(aw[di], bu[ti], acc[di][ti], 0, 0, 0);
    }
    __syncthreads();
  }

  // epilogue: weighted atomic accumulate into out
#pragma unroll
  for (int di = 0; di < 4; ++di)
#pragma unroll
    for (int ti = 0; ti < 4; ++ti) {
      int sidx = wt2 * 64 + ti * 16 + llo;
      int tok = tks[sidx];
      if (tok >= 0) {
        float w = wgs[sidx];
        size_t o = (size_t)tok * DDIM + dt * 128 + wd * 64 + di * 16 + 4 * lhi;
#pragma unroll
        for (int reg = 0; reg < 4; ++reg)
          atomicAdd(out + o + reg, acc[di][ti][reg] * w);
      }
    }
}

extern "C" void kernel_launch(void* const* d_in, const int* in_sizes, int n_in,
                              void* d_out, int out_size, void* d_ws, size_t ws_size,
                              hipStream_t stream) {
  const float* x  = (const float*)d_in[0];
  const float* Wg = (const float*)d_in[1];
  const float* W1 = (const float*)d_in[2];
  const float* W2 = (const float*)d_in[3];
  float* out = (float*)d_out;

  int*   counts = (int*)((char*)d_ws + WS_COUNTS);
  int*   tokl   = (int*)((char*)d_ws + WS_TOKL);
  float* wgtl   = (float*)((char*)d_ws + WS_WGTL);
  unsigned short* XgN = (unsigned short*)((char*)d_ws + WS2_XG);
  unsigned short* W1n = (unsigned short*)((char*)d_ws + WS2_W1);
  unsigned short* W2n = (unsigned short*)((char*)d_ws + WS2_W2);
  unsigned short* UgN = (unsigned short*)((char*)d_ws + WS2_UG);

  hipMemsetAsync(counts, 0, 256, stream);
  hipMemsetAsync(d_out, 0, (size_t)out_size * sizeof(float), stream);

  gate_kernel<<<NTOK / 4, 256, 0, stream>>>(x, Wg, counts, tokl, wgtl);
  convert_w2<<<16384, 256, 0, stream>>>(W1, W2, W1n, W2n);
  gather_x<<<5120, 512, 0, stream>>>(x, counts, tokl, XgN);
  g1<<<NEXP * 16 * 10, 256, 0, stream>>>(W1n, XgN, counts, UgN);
  g2<<<NEXP * 8 * 10, 256, 0, stream>>>(W2n, UgN, counts, tokl, wgtl, out);
}